// Round 4
// baseline (404.838 us; speedup 1.0000x reference)
//
#include <hip/hip_runtime.h>

#define NN 50000
#define NE 800000
#define F_IN 8
#define H 128
#define SCAN_NBLK ((NN + 255) / 256)   // 196
#define BSH 4
#define NB ((NN + 15) >> BSH)          // 3125 buckets, 16 dsts each

typedef unsigned int uint;
typedef unsigned short ushort;

__device__ __forceinline__ ushort f2bf(float f) {
    uint u = __float_as_uint(f);
    uint r = (u + 0x7fffu + ((u >> 16) & 1u)) >> 16;
    return (ushort)r;
}
__device__ __forceinline__ float bflo(uint u) { return __uint_as_float(u << 16); }
__device__ __forceinline__ float bfhi(uint u) { return __uint_as_float(u & 0xffff0000u); }

struct ushort4x { ushort a, b, c, d; };

__global__ void k_zero1(int* __restrict__ a, int n) {
    int i = blockIdx.x * blockDim.x + threadIdx.x;
    if (i < n) a[i] = 0;
}

__global__ void k_indeg(const int* __restrict__ dst, int* __restrict__ indeg) {
    int i = blockIdx.x * blockDim.x + threadIdx.x;
    if (i < NE) atomicAdd(&indeg[dst[i]], 1);
}

__global__ void k_dinv(const int* __restrict__ indeg, float* __restrict__ dinv) {
    int i = blockIdx.x * blockDim.x + threadIdx.x;
    if (i < NN) dinv[i] = rsqrtf((float)(indeg[i] + 1));
}

// ---- multi-block exclusive scan of indeg -> rowstart ----
__global__ __launch_bounds__(256) void k_bsum(const int* __restrict__ indeg,
                                              int* __restrict__ bsum) {
    int b = blockIdx.x;
    int i = b * 256 + threadIdx.x;
    int v = (i < NN) ? indeg[i] : 0;
#pragma unroll
    for (int m = 1; m < 64; m <<= 1) v += __shfl_xor(v, m, 64);
    __shared__ int ws[4];
    if ((threadIdx.x & 63) == 0) ws[threadIdx.x >> 6] = v;
    __syncthreads();
    if (threadIdx.x == 0) bsum[b] = ws[0] + ws[1] + ws[2] + ws[3];
}

__global__ __launch_bounds__(256) void k_bscan(const int* __restrict__ bsum,
                                               int* __restrict__ boff) {
    __shared__ int s[256];
    int t = threadIdx.x;
    s[t] = (t < SCAN_NBLK) ? bsum[t] : 0;
    __syncthreads();
    for (int off = 1; off < 256; off <<= 1) {
        int u = (t >= off) ? s[t - off] : 0;
        __syncthreads();
        s[t] += u;
        __syncthreads();
    }
    boff[t] = (t == 0) ? 0 : s[t - 1];
}

__global__ __launch_bounds__(256) void k_rowstart(const int* __restrict__ indeg,
                                                  const int* __restrict__ boff,
                                                  int* __restrict__ rowstart) {
    int b = blockIdx.x, t = threadIdx.x;
    int i = b * 256 + t;
    int v = (i < NN) ? indeg[i] : 0;
    __shared__ int s[256];
    s[t] = v;
    __syncthreads();
    for (int off = 1; off < 256; off <<= 1) {
        int u = (t >= off) ? s[t - off] : 0;
        __syncthreads();
        s[t] += u;
        __syncthreads();
    }
    if (i < NN) rowstart[i] = boff[b] + s[t] - v;
    if (i == NN - 1) rowstart[NN] = NE;
}

// ---- binned CSR build ----
__global__ void k_init_bincur(const int* __restrict__ rowstart, int* __restrict__ bincur) {
    int i = blockIdx.x * blockDim.x + threadIdx.x;
    if (i < NB) bincur[i] = rowstart[i << BSH];
}

// Pass A: scatter (src,dst,eid) into per-bucket contiguous regions.
__global__ void k_binA(const int* __restrict__ src, const int* __restrict__ dst,
                       int* __restrict__ bincur, int4* __restrict__ bin) {
    int i = blockIdx.x * blockDim.x + threadIdx.x;
    if (i < NE) {
        int d = dst[i];
        int b = d >> BSH;
        int pos = atomicAdd(&bincur[b], 1);
        bin[pos] = make_int4(src[i], d, i, 0);
    }
}

// Pass B: one block per bucket; LDS cursors for its 16 dsts; local scatter to CSR.
__global__ __launch_bounds__(256) void k_binB(const int* __restrict__ rowstart,
                                              const int4* __restrict__ bin,
                                              int2* __restrict__ csr2) {
    int b = blockIdx.x, t = threadIdx.x;
    __shared__ int cur[1 << BSH];
    __shared__ int rs[1 << BSH];
    if (t < (1 << BSH)) {
        cur[t] = 0;
        int n = (b << BSH) + t;
        rs[t] = (n < NN) ? rowstart[n] : NE;
    }
    __syncthreads();
    int base = rowstart[b << BSH];
    int nend = ((b + 1) << BSH);
    int end = rowstart[(nend < NN) ? nend : NN];
    for (int idx = base + t; idx < end; idx += 256) {
        int4 e = bin[idx];
        int ld = e.y & ((1 << BSH) - 1);
        int pos = atomicAdd(&cur[ld], 1);
        csr2[rs[ld] + pos] = make_int2(e.x, e.z);
    }
}

// h[n][j] = sum_k x[n][k] * W1[k][j], bf16 output  (2 nodes / 256-thread block)
__global__ __launch_bounds__(256) void k_xw1(const float* __restrict__ x,
                                             const float* __restrict__ W1,
                                             ushort* __restrict__ h) {
    int t = threadIdx.x;
    int n = blockIdx.x * 2 + (t >> 7);
    int j = t & 127;
    const float* xr = x + n * F_IN;
    float acc = 0.f;
#pragma unroll
    for (int k = 0; k < F_IN; ++k) acc += xr[k] * W1[k * H + j];
    h[n * H + j] = f2bf(acc);
}

// p[n] = relu( h[n]*dinv[n]^2 + sum_{incoming s} h[s]*dinv[s]*dinv[n] + bias )
// h bf16; 64 threads/block, lane t owns columns (2t,2t+1); edge loop unrolled x2.
__global__ __launch_bounds__(64) void k_agg(const ushort* __restrict__ h,
                                            const float* __restrict__ dinv,
                                            const int* __restrict__ rowstart,
                                            const int2* __restrict__ csr2,
                                            const float* __restrict__ bias,
                                            float* __restrict__ p) {
    int n = blockIdx.x, t = threadIdx.x;
    float dn = dinv[n];
    uint us = ((const uint*)(h + (size_t)n * H))[t];
    float w0 = dn * dn;
    float ax = bflo(us) * w0;
    float ay = bfhi(us) * w0;
    int lo = rowstart[n], hi = rowstart[n + 1];
    int i = lo;
    for (; i + 1 < hi; i += 2) {
        int2 e0 = csr2[i];
        int2 e1 = csr2[i + 1];
        uint u0 = ((const uint*)(h + (size_t)e0.x * H))[t];
        uint u1 = ((const uint*)(h + (size_t)e1.x * H))[t];
        float wa = dinv[e0.x] * dn;
        float wb = dinv[e1.x] * dn;
        ax += bflo(u0) * wa + bflo(u1) * wb;
        ay += bfhi(u0) * wa + bfhi(u1) * wb;
    }
    if (i < hi) {
        int2 e0 = csr2[i];
        uint u0 = ((const uint*)(h + (size_t)e0.x * H))[t];
        float wa = dinv[e0.x] * dn;
        ax += bflo(u0) * wa;
        ay += bfhi(u0) * wa;
    }
    float2 bb = ((const float2*)bias)[t];
    float2 r;
    r.x = fmaxf(ax + bb.x, 0.f);
    r.y = fmaxf(ay + bb.y, 0.f);
    ((float2*)p)[(size_t)n * (H / 2) + t] = r;
}

// Y[.,128](bf16) = X[.,128](f32) @ W[128][128]; 32 rows / 256-thread block.
#define GNT 32
__global__ __launch_bounds__(256) void k_gemm128(const float* __restrict__ X,
                                                 const float* __restrict__ W,
                                                 ushort* __restrict__ Y) {
    __shared__ float Ws[128 * 128];
    int t = threadIdx.x;
    int base = blockIdx.x * GNT;
    for (int i = t * 4; i < 128 * 128; i += 256 * 4)
        *(float4*)&Ws[i] = *(const float4*)&W[i];
    __syncthreads();
    int jt = (t & 31) * 4;        // 4 output cols
    int nt = (t >> 5) * 4;        // 4 local rows
    float4 a0 = {0,0,0,0}, a1 = {0,0,0,0}, a2 = {0,0,0,0}, a3 = {0,0,0,0};
    const float* x0 = X + (size_t)(base + nt + 0) * H;
    const float* x1 = X + (size_t)(base + nt + 1) * H;
    const float* x2 = X + (size_t)(base + nt + 2) * H;
    const float* x3 = X + (size_t)(base + nt + 3) * H;
    for (int k0 = 0; k0 < 128; k0 += 4) {
        float4 xv0 = *(const float4*)(x0 + k0);
        float4 xv1 = *(const float4*)(x1 + k0);
        float4 xv2 = *(const float4*)(x2 + k0);
        float4 xv3 = *(const float4*)(x3 + k0);
#pragma unroll
        for (int kk = 0; kk < 4; ++kk) {
            float4 w = *(float4*)&Ws[(k0 + kk) * 128 + jt];
            float v0 = (&xv0.x)[kk], v1 = (&xv1.x)[kk], v2 = (&xv2.x)[kk], v3 = (&xv3.x)[kk];
            a0.x += v0 * w.x; a0.y += v0 * w.y; a0.z += v0 * w.z; a0.w += v0 * w.w;
            a1.x += v1 * w.x; a1.y += v1 * w.y; a1.z += v1 * w.z; a1.w += v1 * w.w;
            a2.x += v2 * w.x; a2.y += v2 * w.y; a2.z += v2 * w.z; a2.w += v2 * w.w;
            a3.x += v3 * w.x; a3.y += v3 * w.y; a3.z += v3 * w.z; a3.w += v3 * w.w;
        }
    }
    ushort4x o;
    if (base + nt + 0 < NN) {
        o.a = f2bf(a0.x); o.b = f2bf(a0.y); o.c = f2bf(a0.z); o.d = f2bf(a0.w);
        *(ushort4x*)&Y[(size_t)(base + nt + 0) * H + jt] = o;
    }
    if (base + nt + 1 < NN) {
        o.a = f2bf(a1.x); o.b = f2bf(a1.y); o.c = f2bf(a1.z); o.d = f2bf(a1.w);
        *(ushort4x*)&Y[(size_t)(base + nt + 1) * H + jt] = o;
    }
    if (base + nt + 2 < NN) {
        o.a = f2bf(a2.x); o.b = f2bf(a2.y); o.c = f2bf(a2.z); o.d = f2bf(a2.w);
        *(ushort4x*)&Y[(size_t)(base + nt + 2) * H + jt] = o;
    }
    if (base + nt + 3 < NN) {
        o.a = f2bf(a3.x); o.b = f2bf(a3.y); o.c = f2bf(a3.z); o.d = f2bf(a3.w);
        *(ushort4x*)&Y[(size_t)(base + nt + 3) * H + jt] = o;
    }
}

// Dst-sorted fused edge stage. One wave per destination node.
__global__ __launch_bounds__(64) void k_edge(const int* __restrict__ rowstart,
                                             const int2* __restrict__ csr2,
                                             const ushort* __restrict__ u,
                                             const ushort* __restrict__ v,
                                             const float* __restrict__ bl1,
                                             const float* __restrict__ Wl2,
                                             const float* __restrict__ bl2,
                                             float* __restrict__ out) {
    int d = blockIdx.x;
    int lane = threadIdx.x;
    int sub = lane >> 4;
    int l16 = lane & 15;
    int lo = rowstart[d], hi = rowstart[d + 1];
    if (lo >= hi) return;

    uint4 vv = *(const uint4*)((const uint*)(v + (size_t)d * H) + l16 * 4);
    float4 ba = *(const float4*)(bl1 + l16 * 8);
    float4 bb = *(const float4*)(bl1 + l16 * 8 + 4);
    float vf0 = bflo(vv.x) + ba.x, vf1 = bfhi(vv.x) + ba.y;
    float vf2 = bflo(vv.y) + ba.z, vf3 = bfhi(vv.y) + ba.w;
    float vf4 = bflo(vv.z) + bb.x, vf5 = bfhi(vv.z) + bb.y;
    float vf6 = bflo(vv.w) + bb.z, vf7 = bfhi(vv.w) + bb.w;
    float4 w0 = *(const float4*)(Wl2 + l16 * 16);
    float4 w1 = *(const float4*)(Wl2 + l16 * 16 + 4);
    float4 w2 = *(const float4*)(Wl2 + l16 * 16 + 8);
    float4 w3 = *(const float4*)(Wl2 + l16 * 16 + 12);
    float b20 = bl2[0], b21 = bl2[1];

    for (int idx = lo + sub; idx < hi; idx += 4) {
        int2 e = csr2[idx];
        uint4 uu = *(const uint4*)((const uint*)(u + (size_t)e.x * H) + l16 * 4);
        float h0 = fmaxf(bflo(uu.x) + vf0, 0.f);
        float h1 = fmaxf(bfhi(uu.x) + vf1, 0.f);
        float h2 = fmaxf(bflo(uu.y) + vf2, 0.f);
        float h3 = fmaxf(bfhi(uu.y) + vf3, 0.f);
        float h4 = fmaxf(bflo(uu.z) + vf4, 0.f);
        float h5 = fmaxf(bfhi(uu.z) + vf5, 0.f);
        float h6 = fmaxf(bflo(uu.w) + vf6, 0.f);
        float h7 = fmaxf(bfhi(uu.w) + vf7, 0.f);
        float p0 = h0 * w0.x + h1 * w0.z + h2 * w1.x + h3 * w1.z
                 + h4 * w2.x + h5 * w2.z + h6 * w3.x + h7 * w3.z;
        float p1 = h0 * w0.y + h1 * w0.w + h2 * w1.y + h3 * w1.w
                 + h4 * w2.y + h5 * w2.w + h6 * w3.y + h7 * w3.w;
#pragma unroll
        for (int m = 1; m < 16; m <<= 1) {
            p0 += __shfl_xor(p0, m, 64);
            p1 += __shfl_xor(p1, m, 64);
        }
        if (l16 == 0) {
            float2 o;
            o.x = fmaxf(p0 + b20, 0.f);
            o.y = fmaxf(p1 + b21, 0.f);
            *(float2*)(out + (size_t)e.y * 2) = o;
        }
    }
}

extern "C" void kernel_launch(void* const* d_in, const int* in_sizes, int n_in,
                              void* d_out, int out_size, void* d_ws, size_t ws_size,
                              hipStream_t stream) {
    const float* x   = (const float*)d_in[0];
    const float* W1  = (const float*)d_in[1];
    const float* b1  = (const float*)d_in[2];
    const float* W2  = (const float*)d_in[3];
    const float* b2  = (const float*)d_in[4];
    const float* Wl1 = (const float*)d_in[5];
    const float* bl1 = (const float*)d_in[6];
    const float* Wl2 = (const float*)d_in[7];
    const float* bl2 = (const float*)d_in[8];
    const int*   ei  = (const int*)d_in[9];
    const int* src = ei;
    const int* dst = ei + NE;
    float* out = (float*)d_out;

    char* ws = (char*)d_ws;
    size_t off = 0;
    auto alloc = [&](size_t bytes) -> void* {
        void* p = ws + off;
        off = (off + bytes + 255) & ~(size_t)255;
        return p;
    };
    const size_t NP = 50048;  // padded rows (gemm tile over-read safety)
    int*    indeg    = (int*)alloc(NN * 4);
    float*  dinv     = (float*)alloc(NN * 4);
    int*    rowstart = (int*)alloc((NN + 1) * 4);
    int*    bsum     = (int*)alloc(256 * 4);
    int*    boff     = (int*)alloc(256 * 4);
    int*    bincur   = (int*)alloc(NB * 4);
    int2*   csr2     = (int2*)alloc((size_t)NE * 8);
    float*  pf       = (float*)alloc(NP * H * 4);    // p1 then p2 (f32); bin aliases this
    ushort* hbf      = (ushort*)alloc(NP * H * 2);   // h1 then h2 (bf16)
    ushort* ubf      = (ushort*)alloc(NP * H * 2);
    ushort* vbf      = (ushort*)alloc(NP * H * 2);
    int4*   bin      = (int4*)pf;  // 12.8MB, dead before first k_agg writes pf

    k_zero1<<<(NN + 255) / 256, 256, 0, stream>>>(indeg, NN);
    k_indeg<<<(NE + 255) / 256, 256, 0, stream>>>(dst, indeg);
    k_dinv<<<(NN + 255) / 256, 256, 0, stream>>>(indeg, dinv);
    k_bsum<<<SCAN_NBLK, 256, 0, stream>>>(indeg, bsum);
    k_bscan<<<1, 256, 0, stream>>>(bsum, boff);
    k_rowstart<<<SCAN_NBLK, 256, 0, stream>>>(indeg, boff, rowstart);
    k_init_bincur<<<(NB + 255) / 256, 256, 0, stream>>>(rowstart, bincur);
    k_binA<<<(NE + 255) / 256, 256, 0, stream>>>(src, dst, bincur, bin);
    k_binB<<<NB, 256, 0, stream>>>(rowstart, bin, csr2);

    k_xw1<<<NN / 2, 256, 0, stream>>>(x, W1, hbf);                        // h1
    k_agg<<<NN, 64, 0, stream>>>(hbf, dinv, rowstart, csr2, b1, pf);      // p1
    k_gemm128<<<(NN + GNT - 1) / GNT, 256, 0, stream>>>(pf, W2, hbf);     // h2
    k_agg<<<NN, 64, 0, stream>>>(hbf, dinv, rowstart, csr2, b2, pf);      // p2
    k_gemm128<<<(NN + GNT - 1) / GNT, 256, 0, stream>>>(pf, Wl1, ubf);            // u
    k_gemm128<<<(NN + GNT - 1) / GNT, 256, 0, stream>>>(pf, Wl1 + 128 * H, vbf);  // v
    k_edge<<<NN, 64, 0, stream>>>(rowstart, csr2, ubf, vbf, bl1, Wl2, bl2, out);
}

// Round 5
// 354.920 us; speedup vs baseline: 1.1406x; 1.1406x over previous
//
#include <hip/hip_runtime.h>

#define NN 50000
#define NE 800000
#define F_IN 8
#define H 128
#define SCAN_NBLK ((NN + 255) / 256)   // 196
#define BSH 7
#define NB ((NN + 127) >> BSH)         // 391 buckets, 128 dsts each
#define EBLK 8192
#define NBE ((NE + EBLK - 1) / EBLK)   // 98 edge blocks

typedef unsigned int uint;
typedef unsigned short ushort;

__device__ __forceinline__ ushort f2bf(float f) {
    uint u = __float_as_uint(f);
    uint r = (u + 0x7fffu + ((u >> 16) & 1u)) >> 16;
    return (ushort)r;
}
__device__ __forceinline__ float bflo(uint u) { return __uint_as_float(u << 16); }
__device__ __forceinline__ float bfhi(uint u) { return __uint_as_float(u & 0xffff0000u); }

struct ushort4x { ushort a, b, c, d; };

__global__ void k_zero1(int* __restrict__ a, int n) {
    int i = blockIdx.x * blockDim.x + threadIdx.x;
    if (i < n) a[i] = 0;
}

__global__ void k_indeg(const int* __restrict__ dst, int* __restrict__ indeg) {
    int i = blockIdx.x * blockDim.x + threadIdx.x;
    if (i < NE) atomicAdd(&indeg[dst[i]], 1);
}

__global__ void k_dinv(const int* __restrict__ indeg, float* __restrict__ dinv) {
    int i = blockIdx.x * blockDim.x + threadIdx.x;
    if (i < NN) dinv[i] = rsqrtf((float)(indeg[i] + 1));
}

// ---- multi-block exclusive scan of indeg -> rowstart ----
__global__ __launch_bounds__(256) void k_bsum(const int* __restrict__ indeg,
                                              int* __restrict__ bsum) {
    int b = blockIdx.x;
    int i = b * 256 + threadIdx.x;
    int v = (i < NN) ? indeg[i] : 0;
#pragma unroll
    for (int m = 1; m < 64; m <<= 1) v += __shfl_xor(v, m, 64);
    __shared__ int ws[4];
    if ((threadIdx.x & 63) == 0) ws[threadIdx.x >> 6] = v;
    __syncthreads();
    if (threadIdx.x == 0) bsum[b] = ws[0] + ws[1] + ws[2] + ws[3];
}

__global__ __launch_bounds__(256) void k_bscan(const int* __restrict__ bsum,
                                               int* __restrict__ boff) {
    __shared__ int s[256];
    int t = threadIdx.x;
    s[t] = (t < SCAN_NBLK) ? bsum[t] : 0;
    __syncthreads();
    for (int off = 1; off < 256; off <<= 1) {
        int u = (t >= off) ? s[t - off] : 0;
        __syncthreads();
        s[t] += u;
        __syncthreads();
    }
    boff[t] = (t == 0) ? 0 : s[t - 1];
}

__global__ __launch_bounds__(256) void k_rowstart(const int* __restrict__ indeg,
                                                  const int* __restrict__ boff,
                                                  int* __restrict__ rowstart) {
    int b = blockIdx.x, t = threadIdx.x;
    int i = b * 256 + t;
    int v = (i < NN) ? indeg[i] : 0;
    __shared__ int s[256];
    s[t] = v;
    __syncthreads();
    for (int off = 1; off < 256; off <<= 1) {
        int u = (t >= off) ? s[t - off] : 0;
        __syncthreads();
        s[t] += u;
        __syncthreads();
    }
    if (i < NN) rowstart[i] = boff[b] + s[t] - v;
    if (i == NN - 1) rowstart[NN] = NE;
}

// ---- deterministic two-phase counting scatter into coarse buckets ----
// Phase 1: per-(edge-block, bucket) histogram. Layout block-major: Hg[e*NB + b].
__global__ __launch_bounds__(512) void k_hist(const int* __restrict__ dst,
                                              int* __restrict__ Hg) {
    __shared__ int h[NB];
    int t = threadIdx.x, blk = blockIdx.x;
    for (int b = t; b < NB; b += 512) h[b] = 0;
    __syncthreads();
    int e0 = blk * EBLK;
    int e1 = e0 + EBLK; if (e1 > NE) e1 = NE;
    for (int i = e0 + t; i < e1; i += 512) atomicAdd(&h[dst[i] >> BSH], 1);
    __syncthreads();
    for (int b = t; b < NB; b += 512) Hg[blk * NB + b] = h[b];
}

// Phase 2: per-bucket running sum across edge blocks -> exact start offsets.
// Thread t owns bucket t; reads/writes are coalesced across threads.
__global__ __launch_bounds__(512) void k_hscan(const int* __restrict__ rowstart,
                                               const int* __restrict__ Hg,
                                               int* __restrict__ Off) {
    int t = threadIdx.x;
    if (t >= NB) return;
    int run = rowstart[t << BSH];
    for (int e = 0; e < NBE; ++e) {
        int c = Hg[e * NB + t];
        Off[e * NB + t] = run;
        run += c;
    }
}

// Phase 3: deterministic scatter. Each (block,bucket) writes a private
// contiguous run -> single-writer, mostly-full cache lines.
__global__ __launch_bounds__(512) void k_scatter(const int* __restrict__ src,
                                                 const int* __restrict__ dst,
                                                 const int* __restrict__ Off,
                                                 int2* __restrict__ bin) {
    __shared__ int cur[NB];
    int t = threadIdx.x, blk = blockIdx.x;
    for (int b = t; b < NB; b += 512) cur[b] = Off[blk * NB + b];
    __syncthreads();
    int e0 = blk * EBLK;
    int e1 = e0 + EBLK; if (e1 > NE) e1 = NE;
    for (int i = e0 + t; i < e1; i += 512) {
        int d = dst[i];
        int b = d >> BSH;
        int pos = atomicAdd(&cur[b], 1);
        bin[pos] = make_int2((src[i] & 0xffff) | ((d & ((1 << BSH) - 1)) << 16), i);
    }
}

// Bucket -> per-dst CSR. One block per bucket; 128 LDS cursors; the bucket's
// CSR window (~16KB) is written by this block only.
__global__ __launch_bounds__(256) void k_binB(const int* __restrict__ rowstart,
                                              const int2* __restrict__ bin,
                                              int2* __restrict__ csr2) {
    int b = blockIdx.x, t = threadIdx.x;
    __shared__ int cur[1 << BSH];
    __shared__ int rs[1 << BSH];
    if (t < (1 << BSH)) {
        cur[t] = 0;
        int n = (b << BSH) + t;
        rs[t] = (n < NN) ? rowstart[n] : NE;
    }
    __syncthreads();
    int base = rowstart[b << BSH];
    int nend = (b + 1) << BSH;
    int end = rowstart[(nend < NN) ? nend : NN];
    for (int idx = base + t; idx < end; idx += 256) {
        int2 e = bin[idx];
        int ld = e.x >> 16;
        int pos = atomicAdd(&cur[ld], 1);
        csr2[rs[ld] + pos] = make_int2(e.x & 0xffff, e.y);
    }
}

// h[n][j] = sum_k x[n][k] * W1[k][j], bf16 output  (2 nodes / 256-thread block)
__global__ __launch_bounds__(256) void k_xw1(const float* __restrict__ x,
                                             const float* __restrict__ W1,
                                             ushort* __restrict__ h) {
    int t = threadIdx.x;
    int n = blockIdx.x * 2 + (t >> 7);
    int j = t & 127;
    const float* xr = x + n * F_IN;
    float acc = 0.f;
#pragma unroll
    for (int k = 0; k < F_IN; ++k) acc += xr[k] * W1[k * H + j];
    h[n * H + j] = f2bf(acc);
}

// p[n] = relu( h[n]*dinv[n]^2 + sum_{incoming s} h[s]*dinv[s]*dinv[n] + bias )
__global__ __launch_bounds__(64) void k_agg(const ushort* __restrict__ h,
                                            const float* __restrict__ dinv,
                                            const int* __restrict__ rowstart,
                                            const int2* __restrict__ csr2,
                                            const float* __restrict__ bias,
                                            float* __restrict__ p) {
    int n = blockIdx.x, t = threadIdx.x;
    float dn = dinv[n];
    uint us = ((const uint*)(h + (size_t)n * H))[t];
    float w0 = dn * dn;
    float ax = bflo(us) * w0;
    float ay = bfhi(us) * w0;
    int lo = rowstart[n], hi = rowstart[n + 1];
    int i = lo;
    for (; i + 1 < hi; i += 2) {
        int2 e0 = csr2[i];
        int2 e1 = csr2[i + 1];
        uint u0 = ((const uint*)(h + (size_t)e0.x * H))[t];
        uint u1 = ((const uint*)(h + (size_t)e1.x * H))[t];
        float wa = dinv[e0.x] * dn;
        float wb = dinv[e1.x] * dn;
        ax += bflo(u0) * wa + bflo(u1) * wb;
        ay += bfhi(u0) * wa + bfhi(u1) * wb;
    }
    if (i < hi) {
        int2 e0 = csr2[i];
        uint u0 = ((const uint*)(h + (size_t)e0.x * H))[t];
        float wa = dinv[e0.x] * dn;
        ax += bflo(u0) * wa;
        ay += bfhi(u0) * wa;
    }
    float2 bb = ((const float2*)bias)[t];
    float2 r;
    r.x = fmaxf(ax + bb.x, 0.f);
    r.y = fmaxf(ay + bb.y, 0.f);
    ((float2*)p)[(size_t)n * (H / 2) + t] = r;
}

// Y[.,128](bf16) = X[.,128](f32) @ W[128][128]; 32 rows / 256-thread block.
#define GNT 32
__global__ __launch_bounds__(256) void k_gemm128(const float* __restrict__ X,
                                                 const float* __restrict__ W,
                                                 ushort* __restrict__ Y) {
    __shared__ float Ws[128 * 128];
    int t = threadIdx.x;
    int base = blockIdx.x * GNT;
    for (int i = t * 4; i < 128 * 128; i += 256 * 4)
        *(float4*)&Ws[i] = *(const float4*)&W[i];
    __syncthreads();
    int jt = (t & 31) * 4;        // 4 output cols
    int nt = (t >> 5) * 4;        // 4 local rows
    float4 a0 = {0,0,0,0}, a1 = {0,0,0,0}, a2 = {0,0,0,0}, a3 = {0,0,0,0};
    const float* x0 = X + (size_t)(base + nt + 0) * H;
    const float* x1 = X + (size_t)(base + nt + 1) * H;
    const float* x2 = X + (size_t)(base + nt + 2) * H;
    const float* x3 = X + (size_t)(base + nt + 3) * H;
    for (int k0 = 0; k0 < 128; k0 += 4) {
        float4 xv0 = *(const float4*)(x0 + k0);
        float4 xv1 = *(const float4*)(x1 + k0);
        float4 xv2 = *(const float4*)(x2 + k0);
        float4 xv3 = *(const float4*)(x3 + k0);
#pragma unroll
        for (int kk = 0; kk < 4; ++kk) {
            float4 w = *(float4*)&Ws[(k0 + kk) * 128 + jt];
            float v0 = (&xv0.x)[kk], v1 = (&xv1.x)[kk], v2 = (&xv2.x)[kk], v3 = (&xv3.x)[kk];
            a0.x += v0 * w.x; a0.y += v0 * w.y; a0.z += v0 * w.z; a0.w += v0 * w.w;
            a1.x += v1 * w.x; a1.y += v1 * w.y; a1.z += v1 * w.z; a1.w += v1 * w.w;
            a2.x += v2 * w.x; a2.y += v2 * w.y; a2.z += v2 * w.z; a2.w += v2 * w.w;
            a3.x += v3 * w.x; a3.y += v3 * w.y; a3.z += v3 * w.z; a3.w += v3 * w.w;
        }
    }
    ushort4x o;
    if (base + nt + 0 < NN) {
        o.a = f2bf(a0.x); o.b = f2bf(a0.y); o.c = f2bf(a0.z); o.d = f2bf(a0.w);
        *(ushort4x*)&Y[(size_t)(base + nt + 0) * H + jt] = o;
    }
    if (base + nt + 1 < NN) {
        o.a = f2bf(a1.x); o.b = f2bf(a1.y); o.c = f2bf(a1.z); o.d = f2bf(a1.w);
        *(ushort4x*)&Y[(size_t)(base + nt + 1) * H + jt] = o;
    }
    if (base + nt + 2 < NN) {
        o.a = f2bf(a2.x); o.b = f2bf(a2.y); o.c = f2bf(a2.z); o.d = f2bf(a2.w);
        *(ushort4x*)&Y[(size_t)(base + nt + 2) * H + jt] = o;
    }
    if (base + nt + 3 < NN) {
        o.a = f2bf(a3.x); o.b = f2bf(a3.y); o.c = f2bf(a3.z); o.d = f2bf(a3.w);
        *(ushort4x*)&Y[(size_t)(base + nt + 3) * H + jt] = o;
    }
}

// Dst-sorted fused edge stage. One wave per destination node.
__global__ __launch_bounds__(64) void k_edge(const int* __restrict__ rowstart,
                                             const int2* __restrict__ csr2,
                                             const ushort* __restrict__ u,
                                             const ushort* __restrict__ v,
                                             const float* __restrict__ bl1,
                                             const float* __restrict__ Wl2,
                                             const float* __restrict__ bl2,
                                             float* __restrict__ out) {
    int d = blockIdx.x;
    int lane = threadIdx.x;
    int sub = lane >> 4;
    int l16 = lane & 15;
    int lo = rowstart[d], hi = rowstart[d + 1];
    if (lo >= hi) return;

    uint4 vv = *(const uint4*)((const uint*)(v + (size_t)d * H) + l16 * 4);
    float4 ba = *(const float4*)(bl1 + l16 * 8);
    float4 bb = *(const float4*)(bl1 + l16 * 8 + 4);
    float vf0 = bflo(vv.x) + ba.x, vf1 = bfhi(vv.x) + ba.y;
    float vf2 = bflo(vv.y) + ba.z, vf3 = bfhi(vv.y) + ba.w;
    float vf4 = bflo(vv.z) + bb.x, vf5 = bfhi(vv.z) + bb.y;
    float vf6 = bflo(vv.w) + bb.z, vf7 = bfhi(vv.w) + bb.w;
    float4 w0 = *(const float4*)(Wl2 + l16 * 16);
    float4 w1 = *(const float4*)(Wl2 + l16 * 16 + 4);
    float4 w2 = *(const float4*)(Wl2 + l16 * 16 + 8);
    float4 w3 = *(const float4*)(Wl2 + l16 * 16 + 12);
    float b20 = bl2[0], b21 = bl2[1];

    for (int idx = lo + sub; idx < hi; idx += 4) {
        int2 e = csr2[idx];
        uint4 uu = *(const uint4*)((const uint*)(u + (size_t)e.x * H) + l16 * 4);
        float h0 = fmaxf(bflo(uu.x) + vf0, 0.f);
        float h1 = fmaxf(bfhi(uu.x) + vf1, 0.f);
        float h2 = fmaxf(bflo(uu.y) + vf2, 0.f);
        float h3 = fmaxf(bfhi(uu.y) + vf3, 0.f);
        float h4 = fmaxf(bflo(uu.z) + vf4, 0.f);
        float h5 = fmaxf(bfhi(uu.z) + vf5, 0.f);
        float h6 = fmaxf(bflo(uu.w) + vf6, 0.f);
        float h7 = fmaxf(bfhi(uu.w) + vf7, 0.f);
        float p0 = h0 * w0.x + h1 * w0.z + h2 * w1.x + h3 * w1.z
                 + h4 * w2.x + h5 * w2.z + h6 * w3.x + h7 * w3.z;
        float p1 = h0 * w0.y + h1 * w0.w + h2 * w1.y + h3 * w1.w
                 + h4 * w2.y + h5 * w2.w + h6 * w3.y + h7 * w3.w;
#pragma unroll
        for (int m = 1; m < 16; m <<= 1) {
            p0 += __shfl_xor(p0, m, 64);
            p1 += __shfl_xor(p1, m, 64);
        }
        if (l16 == 0) {
            float2 o;
            o.x = fmaxf(p0 + b20, 0.f);
            o.y = fmaxf(p1 + b21, 0.f);
            *(float2*)(out + (size_t)e.y * 2) = o;
        }
    }
}

extern "C" void kernel_launch(void* const* d_in, const int* in_sizes, int n_in,
                              void* d_out, int out_size, void* d_ws, size_t ws_size,
                              hipStream_t stream) {
    const float* x   = (const float*)d_in[0];
    const float* W1  = (const float*)d_in[1];
    const float* b1  = (const float*)d_in[2];
    const float* W2  = (const float*)d_in[3];
    const float* b2  = (const float*)d_in[4];
    const float* Wl1 = (const float*)d_in[5];
    const float* bl1 = (const float*)d_in[6];
    const float* Wl2 = (const float*)d_in[7];
    const float* bl2 = (const float*)d_in[8];
    const int*   ei  = (const int*)d_in[9];
    const int* src = ei;
    const int* dst = ei + NE;
    float* out = (float*)d_out;

    char* ws = (char*)d_ws;
    size_t off = 0;
    auto alloc = [&](size_t bytes) -> void* {
        void* p = ws + off;
        off = (off + bytes + 255) & ~(size_t)255;
        return p;
    };
    const size_t NP = 50048;  // padded rows (gemm tile over-read safety)
    int*    indeg    = (int*)alloc(NN * 4);
    float*  dinv     = (float*)alloc(NN * 4);
    int*    rowstart = (int*)alloc((NN + 1) * 4);
    int*    bsum     = (int*)alloc(256 * 4);
    int*    boff     = (int*)alloc(256 * 4);
    int*    Hg       = (int*)alloc((size_t)NBE * NB * 4);
    int*    Offb     = (int*)alloc((size_t)NBE * NB * 4);
    int2*   csr2     = (int2*)alloc((size_t)NE * 8);
    float*  pf       = (float*)alloc(NP * H * 4);    // p1 then p2 (f32); bin aliases this
    ushort* hbf      = (ushort*)alloc(NP * H * 2);   // h1 then h2 (bf16)
    ushort* ubf      = (ushort*)alloc(NP * H * 2);
    ushort* vbf      = (ushort*)alloc(NP * H * 2);
    int2*   bin      = (int2*)pf;  // 6.4MB, dead before first k_agg writes pf

    k_zero1<<<(NN + 255) / 256, 256, 0, stream>>>(indeg, NN);
    k_indeg<<<(NE + 255) / 256, 256, 0, stream>>>(dst, indeg);
    k_dinv<<<(NN + 255) / 256, 256, 0, stream>>>(indeg, dinv);
    k_bsum<<<SCAN_NBLK, 256, 0, stream>>>(indeg, bsum);
    k_bscan<<<1, 256, 0, stream>>>(bsum, boff);
    k_rowstart<<<SCAN_NBLK, 256, 0, stream>>>(indeg, boff, rowstart);
    k_hist<<<NBE, 512, 0, stream>>>(dst, Hg);
    k_hscan<<<1, 512, 0, stream>>>(rowstart, Hg, Offb);
    k_scatter<<<NBE, 512, 0, stream>>>(src, dst, Offb, bin);
    k_binB<<<NB, 256, 0, stream>>>(rowstart, bin, csr2);

    k_xw1<<<NN / 2, 256, 0, stream>>>(x, W1, hbf);                        // h1
    k_agg<<<NN, 64, 0, stream>>>(hbf, dinv, rowstart, csr2, b1, pf);      // p1
    k_gemm128<<<(NN + GNT - 1) / GNT, 256, 0, stream>>>(pf, W2, hbf);     // h2
    k_agg<<<NN, 64, 0, stream>>>(hbf, dinv, rowstart, csr2, b2, pf);      // p2
    k_gemm128<<<(NN + GNT - 1) / GNT, 256, 0, stream>>>(pf, Wl1, ubf);            // u
    k_gemm128<<<(NN + GNT - 1) / GNT, 256, 0, stream>>>(pf, Wl1 + 128 * H, vbf);  // v
    k_edge<<<NN, 64, 0, stream>>>(rowstart, csr2, ubf, vbf, bl1, Wl2, bl2, out);
}

// Round 7
// 349.326 us; speedup vs baseline: 1.1589x; 1.0160x over previous
//
#include <hip/hip_runtime.h>

#define NN 50000
#define NE 800000
#define F_IN 8
#define H 128
#define SCAN_NBLK ((NN + 255) / 256)   // 196
#define BSH 7
#define NB ((NN + 127) >> BSH)         // 391 buckets, 128 dsts each
#define EBLK 8192
#define NBE ((NE + EBLK - 1) / EBLK)   // 98 edge blocks

typedef unsigned int uint;
typedef unsigned short ushort;

__device__ __forceinline__ ushort f2bf(float f) {
    uint u = __float_as_uint(f);
    uint r = (u + 0x7fffu + ((u >> 16) & 1u)) >> 16;
    return (ushort)r;
}
__device__ __forceinline__ float bflo(uint u) { return __uint_as_float(u << 16); }
__device__ __forceinline__ float bfhi(uint u) { return __uint_as_float(u & 0xffff0000u); }

struct ushort4x { ushort a, b, c, d; };

__global__ void k_zero1(int* __restrict__ a, int n) {
    int i = blockIdx.x * blockDim.x + threadIdx.x;
    if (i < n) a[i] = 0;
}

__global__ void k_indeg(const int* __restrict__ dst, int* __restrict__ indeg) {
    int i = blockIdx.x * blockDim.x + threadIdx.x;
    if (i < NE) atomicAdd(&indeg[dst[i]], 1);
}

__global__ void k_dinv(const int* __restrict__ indeg, float* __restrict__ dinv) {
    int i = blockIdx.x * blockDim.x + threadIdx.x;
    if (i < NN) dinv[i] = rsqrtf((float)(indeg[i] + 1));
}

// ---- multi-block exclusive scan of indeg -> rowstart ----
__global__ __launch_bounds__(256) void k_bsum(const int* __restrict__ indeg,
                                              int* __restrict__ bsum) {
    int b = blockIdx.x;
    int i = b * 256 + threadIdx.x;
    int v = (i < NN) ? indeg[i] : 0;
#pragma unroll
    for (int m = 1; m < 64; m <<= 1) v += __shfl_xor(v, m, 64);
    __shared__ int ws[4];
    if ((threadIdx.x & 63) == 0) ws[threadIdx.x >> 6] = v;
    __syncthreads();
    if (threadIdx.x == 0) bsum[b] = ws[0] + ws[1] + ws[2] + ws[3];
}

__global__ __launch_bounds__(256) void k_bscan(const int* __restrict__ bsum,
                                               int* __restrict__ boff) {
    __shared__ int s[256];
    int t = threadIdx.x;
    s[t] = (t < SCAN_NBLK) ? bsum[t] : 0;
    __syncthreads();
    for (int off = 1; off < 256; off <<= 1) {
        int u = (t >= off) ? s[t - off] : 0;
        __syncthreads();
        s[t] += u;
        __syncthreads();
    }
    boff[t] = (t == 0) ? 0 : s[t - 1];
}

__global__ __launch_bounds__(256) void k_rowstart(const int* __restrict__ indeg,
                                                  const int* __restrict__ boff,
                                                  int* __restrict__ rowstart) {
    int b = blockIdx.x, t = threadIdx.x;
    int i = b * 256 + t;
    int v = (i < NN) ? indeg[i] : 0;
    __shared__ int s[256];
    s[t] = v;
    __syncthreads();
    for (int off = 1; off < 256; off <<= 1) {
        int u = (t >= off) ? s[t - off] : 0;
        __syncthreads();
        s[t] += u;
        __syncthreads();
    }
    if (i < NN) rowstart[i] = boff[b] + s[t] - v;
    if (i == NN - 1) rowstart[NN] = NE;
}

// ---- deterministic two-phase counting scatter into coarse buckets ----
__global__ __launch_bounds__(512) void k_hist(const int* __restrict__ dst,
                                              int* __restrict__ Hg) {
    __shared__ int h[NB];
    int t = threadIdx.x, blk = blockIdx.x;
    for (int b = t; b < NB; b += 512) h[b] = 0;
    __syncthreads();
    int e0 = blk * EBLK;
    int e1 = e0 + EBLK; if (e1 > NE) e1 = NE;
    for (int i = e0 + t; i < e1; i += 512) atomicAdd(&h[dst[i] >> BSH], 1);
    __syncthreads();
    for (int b = t; b < NB; b += 512) Hg[blk * NB + b] = h[b];
}

__global__ __launch_bounds__(512) void k_hscan(const int* __restrict__ rowstart,
                                               const int* __restrict__ Hg,
                                               int* __restrict__ Off) {
    int t = threadIdx.x;
    if (t >= NB) return;
    int run = rowstart[t << BSH];
    for (int e = 0; e < NBE; ++e) {
        int c = Hg[e * NB + t];
        Off[e * NB + t] = run;
        run += c;
    }
}

__global__ __launch_bounds__(512) void k_scatter(const int* __restrict__ src,
                                                 const int* __restrict__ dst,
                                                 const int* __restrict__ Off,
                                                 int2* __restrict__ bin) {
    __shared__ int cur[NB];
    int t = threadIdx.x, blk = blockIdx.x;
    for (int b = t; b < NB; b += 512) cur[b] = Off[blk * NB + b];
    __syncthreads();
    int e0 = blk * EBLK;
    int e1 = e0 + EBLK; if (e1 > NE) e1 = NE;
    for (int i = e0 + t; i < e1; i += 512) {
        int d = dst[i];
        int b = d >> BSH;
        int pos = atomicAdd(&cur[b], 1);
        bin[pos] = make_int2((src[i] & 0xffff) | ((d & ((1 << BSH) - 1)) << 16), i);
    }
}

// Bucket -> per-dst CSR. csr2.x packs (src | dst<<16) [dst via uint math]; csr2.y = edge id.
__global__ __launch_bounds__(256) void k_binB(const int* __restrict__ rowstart,
                                              const int2* __restrict__ bin,
                                              int2* __restrict__ csr2) {
    int b = blockIdx.x, t = threadIdx.x;
    __shared__ int cur[1 << BSH];
    __shared__ int rs[1 << BSH];
    if (t < (1 << BSH)) {
        cur[t] = 0;
        int n = (b << BSH) + t;
        rs[t] = (n < NN) ? rowstart[n] : NE;
    }
    __syncthreads();
    int base = rowstart[b << BSH];
    int nend = (b + 1) << BSH;
    int end = rowstart[(nend < NN) ? nend : NN];
    for (int idx = base + t; idx < end; idx += 256) {
        int2 e = bin[idx];
        int ld = (int)((uint)e.x >> 16);   // 7 bits, safe
        uint d = (uint)((b << BSH) + ld);
        int pos = atomicAdd(&cur[ld], 1);
        csr2[rs[ld] + pos] = make_int2((int)(((uint)e.x & 0xffffu) | (d << 16)), e.y);
    }
}

// h[n][j] = sum_k x[n][k] * W1[k][j], bf16 output  (2 nodes / 256-thread block)
__global__ __launch_bounds__(256) void k_xw1(const float* __restrict__ x,
                                             const float* __restrict__ W1,
                                             ushort* __restrict__ h) {
    int t = threadIdx.x;
    int n = blockIdx.x * 2 + (t >> 7);
    int j = t & 127;
    const float* xr = x + n * F_IN;
    float acc = 0.f;
#pragma unroll
    for (int k = 0; k < F_IN; ++k) acc += xr[k] * W1[k * H + j];
    h[n * H + j] = f2bf(acc);
}

// p[n] = relu( h[n]*dinv[n]^2 + sum_{incoming s} h[s]*dinv[s]*dinv[n] + bias )
// 4 nodes per 256-thread block (wave per node); edge loop unrolled x4 for MLP.
__global__ __launch_bounds__(256) void k_agg(const ushort* __restrict__ h,
                                             const float* __restrict__ dinv,
                                             const int* __restrict__ rowstart,
                                             const int2* __restrict__ csr2,
                                             const float* __restrict__ bias,
                                             float* __restrict__ p) {
    int n = blockIdx.x * 4 + (threadIdx.x >> 6);
    int t = threadIdx.x & 63;
    float dn = dinv[n];
    uint us = ((const uint*)(h + (size_t)n * H))[t];
    float w0 = dn * dn;
    float ax = bflo(us) * w0;
    float ay = bfhi(us) * w0;
    int lo = rowstart[n], hi = rowstart[n + 1];
    int i = lo;
    for (; i + 3 < hi; i += 4) {
        int2 e0 = csr2[i];
        int2 e1 = csr2[i + 1];
        int2 e2 = csr2[i + 2];
        int2 e3 = csr2[i + 3];
        int s0 = e0.x & 0xffff, s1 = e1.x & 0xffff, s2 = e2.x & 0xffff, s3 = e3.x & 0xffff;
        uint u0 = ((const uint*)(h + (size_t)s0 * H))[t];
        uint u1 = ((const uint*)(h + (size_t)s1 * H))[t];
        uint u2 = ((const uint*)(h + (size_t)s2 * H))[t];
        uint u3 = ((const uint*)(h + (size_t)s3 * H))[t];
        float wa = dinv[s0] * dn;
        float wb = dinv[s1] * dn;
        float wc = dinv[s2] * dn;
        float wd = dinv[s3] * dn;
        ax += bflo(u0) * wa + bflo(u1) * wb + bflo(u2) * wc + bflo(u3) * wd;
        ay += bfhi(u0) * wa + bfhi(u1) * wb + bfhi(u2) * wc + bfhi(u3) * wd;
    }
    for (; i < hi; ++i) {
        int2 e0 = csr2[i];
        int s0 = e0.x & 0xffff;
        uint u0 = ((const uint*)(h + (size_t)s0 * H))[t];
        float wa = dinv[s0] * dn;
        ax += bflo(u0) * wa;
        ay += bfhi(u0) * wa;
    }
    float2 bb = ((const float2*)bias)[t];
    float2 r;
    r.x = fmaxf(ax + bb.x, 0.f);
    r.y = fmaxf(ay + bb.y, 0.f);
    ((float2*)p)[(size_t)n * (H / 2) + t] = r;
}

// Y[.,128](bf16) = X[.,128](f32) @ W[128][128]; 32 rows / 256-thread block.
#define GNT 32
__global__ __launch_bounds__(256) void k_gemm128(const float* __restrict__ X,
                                                 const float* __restrict__ W,
                                                 ushort* __restrict__ Y) {
    __shared__ float Ws[128 * 128];
    int t = threadIdx.x;
    int base = blockIdx.x * GNT;
    for (int i = t * 4; i < 128 * 128; i += 256 * 4)
        *(float4*)&Ws[i] = *(const float4*)&W[i];
    __syncthreads();
    int jt = (t & 31) * 4;        // 4 output cols
    int nt = (t >> 5) * 4;        // 4 local rows
    float4 a0 = {0,0,0,0}, a1 = {0,0,0,0}, a2 = {0,0,0,0}, a3 = {0,0,0,0};
    const float* x0 = X + (size_t)(base + nt + 0) * H;
    const float* x1 = X + (size_t)(base + nt + 1) * H;
    const float* x2 = X + (size_t)(base + nt + 2) * H;
    const float* x3 = X + (size_t)(base + nt + 3) * H;
    for (int k0 = 0; k0 < 128; k0 += 4) {
        float4 xv0 = *(const float4*)(x0 + k0);
        float4 xv1 = *(const float4*)(x1 + k0);
        float4 xv2 = *(const float4*)(x2 + k0);
        float4 xv3 = *(const float4*)(x3 + k0);
#pragma unroll
        for (int kk = 0; kk < 4; ++kk) {
            float4 w = *(float4*)&Ws[(k0 + kk) * 128 + jt];
            float v0 = (&xv0.x)[kk], v1 = (&xv1.x)[kk], v2 = (&xv2.x)[kk], v3 = (&xv3.x)[kk];
            a0.x += v0 * w.x; a0.y += v0 * w.y; a0.z += v0 * w.z; a0.w += v0 * w.w;
            a1.x += v1 * w.x; a1.y += v1 * w.y; a1.z += v1 * w.z; a1.w += v1 * w.w;
            a2.x += v2 * w.x; a2.y += v2 * w.y; a2.z += v2 * w.z; a2.w += v2 * w.w;
            a3.x += v3 * w.x; a3.y += v3 * w.y; a3.z += v3 * w.z; a3.w += v3 * w.w;
        }
    }
    ushort4x o;
    if (base + nt + 0 < NN) {
        o.a = f2bf(a0.x); o.b = f2bf(a0.y); o.c = f2bf(a0.z); o.d = f2bf(a0.w);
        *(ushort4x*)&Y[(size_t)(base + nt + 0) * H + jt] = o;
    }
    if (base + nt + 1 < NN) {
        o.a = f2bf(a1.x); o.b = f2bf(a1.y); o.c = f2bf(a1.z); o.d = f2bf(a1.w);
        *(ushort4x*)&Y[(size_t)(base + nt + 1) * H + jt] = o;
    }
    if (base + nt + 2 < NN) {
        o.a = f2bf(a2.x); o.b = f2bf(a2.y); o.c = f2bf(a2.z); o.d = f2bf(a2.w);
        *(ushort4x*)&Y[(size_t)(base + nt + 2) * H + jt] = o;
    }
    if (base + nt + 3 < NN) {
        o.a = f2bf(a3.x); o.b = f2bf(a3.y); o.c = f2bf(a3.z); o.d = f2bf(a3.w);
        *(ushort4x*)&Y[(size_t)(base + nt + 3) * H + jt] = o;
    }
}

// Edge-parallel fused edge stage: 16-lane group per CSR entry, 2 entries/group.
#define EPB 32   // csr entries per 256-thread block
__global__ __launch_bounds__(256) void k_edge(const int2* __restrict__ csr2,
                                              const ushort* __restrict__ u,
                                              const ushort* __restrict__ v,
                                              const float* __restrict__ bl1,
                                              const float* __restrict__ Wl2,
                                              const float* __restrict__ bl2,
                                              float* __restrict__ out) {
    int g = threadIdx.x >> 4;          // group 0..15
    int l16 = threadIdx.x & 15;
    int base = blockIdx.x * EPB;

    float4 ba = *(const float4*)(bl1 + l16 * 8);
    float4 bb = *(const float4*)(bl1 + l16 * 8 + 4);
    float4 w0 = *(const float4*)(Wl2 + l16 * 16);
    float4 w1 = *(const float4*)(Wl2 + l16 * 16 + 4);
    float4 w2 = *(const float4*)(Wl2 + l16 * 16 + 8);
    float4 w3 = *(const float4*)(Wl2 + l16 * 16 + 12);
    float b20 = bl2[0], b21 = bl2[1];

    int2 eA = csr2[base + g];
    int2 eB = csr2[base + g + 16];
    uint sA = (uint)eA.x & 0xffffu, dA = (uint)eA.x >> 16;   // logical shift!
    uint sB = (uint)eB.x & 0xffffu, dB = (uint)eB.x >> 16;
    uint4 uA = *(const uint4*)((const uint*)(u + (size_t)sA * H) + l16 * 4);
    uint4 vA = *(const uint4*)((const uint*)(v + (size_t)dA * H) + l16 * 4);
    uint4 uB = *(const uint4*)((const uint*)(u + (size_t)sB * H) + l16 * 4);
    uint4 vB = *(const uint4*)((const uint*)(v + (size_t)dB * H) + l16 * 4);

#pragma unroll
    for (int q = 0; q < 2; ++q) {
        uint4 uu = q ? uB : uA;
        uint4 vv = q ? vB : vA;
        int eid = q ? eB.y : eA.y;
        float h0 = fmaxf(bflo(uu.x) + bflo(vv.x) + ba.x, 0.f);
        float h1 = fmaxf(bfhi(uu.x) + bfhi(vv.x) + ba.y, 0.f);
        float h2 = fmaxf(bflo(uu.y) + bflo(vv.y) + ba.z, 0.f);
        float h3 = fmaxf(bfhi(uu.y) + bfhi(vv.y) + ba.w, 0.f);
        float h4 = fmaxf(bflo(uu.z) + bflo(vv.z) + bb.x, 0.f);
        float h5 = fmaxf(bfhi(uu.z) + bfhi(vv.z) + bb.y, 0.f);
        float h6 = fmaxf(bflo(uu.w) + bflo(vv.w) + bb.z, 0.f);
        float h7 = fmaxf(bfhi(uu.w) + bfhi(vv.w) + bb.w, 0.f);
        float p0 = h0 * w0.x + h1 * w0.z + h2 * w1.x + h3 * w1.z
                 + h4 * w2.x + h5 * w2.z + h6 * w3.x + h7 * w3.z;
        float p1 = h0 * w0.y + h1 * w0.w + h2 * w1.y + h3 * w1.w
                 + h4 * w2.y + h5 * w2.w + h6 * w3.y + h7 * w3.w;
#pragma unroll
        for (int m = 1; m < 16; m <<= 1) {
            p0 += __shfl_xor(p0, m, 64);
            p1 += __shfl_xor(p1, m, 64);
        }
        if (l16 == 0) {
            float2 o;
            o.x = fmaxf(p0 + b20, 0.f);
            o.y = fmaxf(p1 + b21, 0.f);
            *(float2*)(out + (size_t)eid * 2) = o;
        }
    }
}

extern "C" void kernel_launch(void* const* d_in, const int* in_sizes, int n_in,
                              void* d_out, int out_size, void* d_ws, size_t ws_size,
                              hipStream_t stream) {
    const float* x   = (const float*)d_in[0];
    const float* W1  = (const float*)d_in[1];
    const float* b1  = (const float*)d_in[2];
    const float* W2  = (const float*)d_in[3];
    const float* b2  = (const float*)d_in[4];
    const float* Wl1 = (const float*)d_in[5];
    const float* bl1 = (const float*)d_in[6];
    const float* Wl2 = (const float*)d_in[7];
    const float* bl2 = (const float*)d_in[8];
    const int*   ei  = (const int*)d_in[9];
    const int* src = ei;
    const int* dst = ei + NE;
    float* out = (float*)d_out;

    char* ws = (char*)d_ws;
    size_t off = 0;
    auto alloc = [&](size_t bytes) -> void* {
        void* p = ws + off;
        off = (off + bytes + 255) & ~(size_t)255;
        return p;
    };
    const size_t NP = 50048;  // padded rows (gemm tile over-read safety)
    int*    indeg    = (int*)alloc(NN * 4);
    float*  dinv     = (float*)alloc(NN * 4);
    int*    rowstart = (int*)alloc((NN + 1) * 4);
    int*    bsum     = (int*)alloc(256 * 4);
    int*    boff     = (int*)alloc(256 * 4);
    int*    Hg       = (int*)alloc((size_t)NBE * NB * 4);
    int*    Offb     = (int*)alloc((size_t)NBE * NB * 4);
    int2*   csr2     = (int2*)alloc((size_t)NE * 8);
    float*  pf       = (float*)alloc(NP * H * 4);    // p1 then p2 (f32); bin aliases this
    ushort* hbf      = (ushort*)alloc(NP * H * 2);   // h1 then h2 (bf16)
    ushort* ubf      = (ushort*)alloc(NP * H * 2);
    ushort* vbf      = (ushort*)alloc(NP * H * 2);
    int2*   bin      = (int2*)pf;  // 6.4MB, dead before first k_agg writes pf

    k_zero1<<<(NN + 255) / 256, 256, 0, stream>>>(indeg, NN);
    k_indeg<<<(NE + 255) / 256, 256, 0, stream>>>(dst, indeg);
    k_dinv<<<(NN + 255) / 256, 256, 0, stream>>>(indeg, dinv);
    k_bsum<<<SCAN_NBLK, 256, 0, stream>>>(indeg, bsum);
    k_bscan<<<1, 256, 0, stream>>>(bsum, boff);
    k_rowstart<<<SCAN_NBLK, 256, 0, stream>>>(indeg, boff, rowstart);
    k_hist<<<NBE, 512, 0, stream>>>(dst, Hg);
    k_hscan<<<1, 512, 0, stream>>>(rowstart, Hg, Offb);
    k_scatter<<<NBE, 512, 0, stream>>>(src, dst, Offb, bin);
    k_binB<<<NB, 256, 0, stream>>>(rowstart, bin, csr2);

    k_xw1<<<NN / 2, 256, 0, stream>>>(x, W1, hbf);                        // h1
    k_agg<<<NN / 4, 256, 0, stream>>>(hbf, dinv, rowstart, csr2, b1, pf); // p1
    k_gemm128<<<(NN + GNT - 1) / GNT, 256, 0, stream>>>(pf, W2, hbf);     // h2
    k_agg<<<NN / 4, 256, 0, stream>>>(hbf, dinv, rowstart, csr2, b2, pf); // p2
    k_gemm128<<<(NN + GNT - 1) / GNT, 256, 0, stream>>>(pf, Wl1, ubf);            // u
    k_gemm128<<<(NN + GNT - 1) / GNT, 256, 0, stream>>>(pf, Wl1 + 128 * H, vbf);  // v
    k_edge<<<NE / EPB, 256, 0, stream>>>(csr2, ubf, vbf, bl1, Wl2, bl2, out);
}

// Round 8
// 336.893 us; speedup vs baseline: 1.2017x; 1.0369x over previous
//
#include <hip/hip_runtime.h>

#define NN 50000
#define NE 800000
#define F_IN 8
#define H 128
#define SCAN_NBLK ((NN + 255) / 256)   // 196
#define BSH 7
#define NB ((NN + 127) >> BSH)         // 391 buckets, 128 dsts each
#define EBLK 4096
#define NBE ((NE + EBLK - 1) / EBLK)   // 196 edge blocks

typedef unsigned int uint;
typedef unsigned short ushort;

__device__ __forceinline__ ushort f2bf(float f) {
    uint u = __float_as_uint(f);
    uint r = (u + 0x7fffu + ((u >> 16) & 1u)) >> 16;
    return (ushort)r;
}
__device__ __forceinline__ float bflo(uint u) { return __uint_as_float(u << 16); }
__device__ __forceinline__ float bfhi(uint u) { return __uint_as_float(u & 0xffff0000u); }

struct ushort4x { ushort a, b, c, d; };

__global__ void k_zero1(int* __restrict__ a, int n) {
    int i = blockIdx.x * blockDim.x + threadIdx.x;
    if (i < n) a[i] = 0;
}

__global__ void k_indeg(const int* __restrict__ dst, int* __restrict__ indeg) {
    int i = blockIdx.x * blockDim.x + threadIdx.x;
    if (i < NE) atomicAdd(&indeg[dst[i]], 1);
}

__global__ void k_dinv(const int* __restrict__ indeg, float* __restrict__ dinv) {
    int i = blockIdx.x * blockDim.x + threadIdx.x;
    if (i < NN) dinv[i] = rsqrtf((float)(indeg[i] + 1));
}

// ---- multi-block exclusive scan of indeg -> rowstart ----
__global__ __launch_bounds__(256) void k_bsum(const int* __restrict__ indeg,
                                              int* __restrict__ bsum) {
    int b = blockIdx.x;
    int i = b * 256 + threadIdx.x;
    int v = (i < NN) ? indeg[i] : 0;
#pragma unroll
    for (int m = 1; m < 64; m <<= 1) v += __shfl_xor(v, m, 64);
    __shared__ int ws[4];
    if ((threadIdx.x & 63) == 0) ws[threadIdx.x >> 6] = v;
    __syncthreads();
    if (threadIdx.x == 0) bsum[b] = ws[0] + ws[1] + ws[2] + ws[3];
}

__global__ __launch_bounds__(256) void k_bscan(const int* __restrict__ bsum,
                                               int* __restrict__ boff) {
    __shared__ int s[256];
    int t = threadIdx.x;
    s[t] = (t < SCAN_NBLK) ? bsum[t] : 0;
    __syncthreads();
    for (int off = 1; off < 256; off <<= 1) {
        int u = (t >= off) ? s[t - off] : 0;
        __syncthreads();
        s[t] += u;
        __syncthreads();
    }
    boff[t] = (t == 0) ? 0 : s[t - 1];
}

__global__ __launch_bounds__(256) void k_rowstart(const int* __restrict__ indeg,
                                                  const int* __restrict__ boff,
                                                  int* __restrict__ rowstart) {
    int b = blockIdx.x, t = threadIdx.x;
    int i = b * 256 + t;
    int v = (i < NN) ? indeg[i] : 0;
    __shared__ int s[256];
    s[t] = v;
    __syncthreads();
    for (int off = 1; off < 256; off <<= 1) {
        int u = (t >= off) ? s[t - off] : 0;
        __syncthreads();
        s[t] += u;
        __syncthreads();
    }
    if (i < NN) rowstart[i] = boff[b] + s[t] - v;
    if (i == NN - 1) rowstart[NN] = NE;
}

// ---- deterministic two-phase counting scatter into coarse buckets ----
__global__ __launch_bounds__(512) void k_hist(const int* __restrict__ dst,
                                              int* __restrict__ Hg) {
    __shared__ int h[NB];
    int t = threadIdx.x, blk = blockIdx.x;
    for (int b = t; b < NB; b += 512) h[b] = 0;
    __syncthreads();
    int e0 = blk * EBLK;
    int e1 = e0 + EBLK; if (e1 > NE) e1 = NE;
    for (int i = e0 + t; i < e1; i += 512) atomicAdd(&h[dst[i] >> BSH], 1);
    __syncthreads();
    for (int b = t; b < NB; b += 512) Hg[blk * NB + b] = h[b];
}

__global__ __launch_bounds__(512) void k_hscan(const int* __restrict__ rowstart,
                                               const int* __restrict__ Hg,
                                               int* __restrict__ Off) {
    int t = threadIdx.x;
    if (t >= NB) return;
    int run = rowstart[t << BSH];
    for (int e = 0; e < NBE; ++e) {
        int c = Hg[e * NB + t];
        Off[e * NB + t] = run;
        run += c;
    }
}

__global__ __launch_bounds__(512) void k_scatter(const int* __restrict__ src,
                                                 const int* __restrict__ dst,
                                                 const int* __restrict__ Off,
                                                 int2* __restrict__ bin) {
    __shared__ int cur[NB];
    int t = threadIdx.x, blk = blockIdx.x;
    for (int b = t; b < NB; b += 512) cur[b] = Off[blk * NB + b];
    __syncthreads();
    int e0 = blk * EBLK;
    int e1 = e0 + EBLK; if (e1 > NE) e1 = NE;
    for (int i = e0 + t; i < e1; i += 512) {
        int d = dst[i];
        int b = d >> BSH;
        int pos = atomicAdd(&cur[b], 1);
        bin[pos] = make_int2((src[i] & 0xffff) | ((d & ((1 << BSH) - 1)) << 16), i);
    }
}

// Bucket -> per-dst CSR. csr2.x packs (src | dst<<16) [uint math]; csr2.y = edge id.
__global__ __launch_bounds__(256) void k_binB(const int* __restrict__ rowstart,
                                              const int2* __restrict__ bin,
                                              int2* __restrict__ csr2) {
    int b = blockIdx.x, t = threadIdx.x;
    __shared__ int cur[1 << BSH];
    __shared__ int rs[1 << BSH];
    if (t < (1 << BSH)) {
        cur[t] = 0;
        int n = (b << BSH) + t;
        rs[t] = (n < NN) ? rowstart[n] : NE;
    }
    __syncthreads();
    int base = rowstart[b << BSH];
    int nend = (b + 1) << BSH;
    int end = rowstart[(nend < NN) ? nend : NN];
    for (int idx = base + t; idx < end; idx += 256) {
        int2 e = bin[idx];
        int ld = (int)((uint)e.x >> 16);   // 7 bits, safe
        uint d = (uint)((b << BSH) + ld);
        int pos = atomicAdd(&cur[ld], 1);
        csr2[rs[ld] + pos] = make_int2((int)(((uint)e.x & 0xffffu) | (d << 16)), e.y);
    }
}

// h[n][j] = sum_k x[n][k] * W1[k][j], bf16 output  (2 nodes / 256-thread block)
__global__ __launch_bounds__(256) void k_xw1(const float* __restrict__ x,
                                             const float* __restrict__ W1,
                                             ushort* __restrict__ h) {
    int t = threadIdx.x;
    int n = blockIdx.x * 2 + (t >> 7);
    int j = t & 127;
    const float* xr = x + n * F_IN;
    float acc = 0.f;
#pragma unroll
    for (int k = 0; k < F_IN; ++k) acc += xr[k] * W1[k * H + j];
    h[n * H + j] = f2bf(acc);
}

// p[n] = relu( h[n]*dinv[n]^2 + sum_{incoming s} h[s]*dinv[s]*dinv[n] + bias )
// 4 nodes per 256-thread block (wave per node); edge loop unrolled x8 for MLP.
__global__ __launch_bounds__(256) void k_agg(const ushort* __restrict__ h,
                                             const float* __restrict__ dinv,
                                             const int* __restrict__ rowstart,
                                             const int2* __restrict__ csr2,
                                             const float* __restrict__ bias,
                                             float* __restrict__ p) {
    int n = blockIdx.x * 4 + (threadIdx.x >> 6);
    int t = threadIdx.x & 63;
    float dn = dinv[n];
    uint us = ((const uint*)(h + (size_t)n * H))[t];
    float w0 = dn * dn;
    float ax = bflo(us) * w0;
    float ay = bfhi(us) * w0;
    int lo = rowstart[n], hi = rowstart[n + 1];
    int i = lo;
    for (; i + 7 < hi; i += 8) {
        int s0 = csr2[i + 0].x & 0xffff;
        int s1 = csr2[i + 1].x & 0xffff;
        int s2 = csr2[i + 2].x & 0xffff;
        int s3 = csr2[i + 3].x & 0xffff;
        int s4 = csr2[i + 4].x & 0xffff;
        int s5 = csr2[i + 5].x & 0xffff;
        int s6 = csr2[i + 6].x & 0xffff;
        int s7 = csr2[i + 7].x & 0xffff;
        uint u0 = ((const uint*)(h + (size_t)s0 * H))[t];
        uint u1 = ((const uint*)(h + (size_t)s1 * H))[t];
        uint u2 = ((const uint*)(h + (size_t)s2 * H))[t];
        uint u3 = ((const uint*)(h + (size_t)s3 * H))[t];
        uint u4 = ((const uint*)(h + (size_t)s4 * H))[t];
        uint u5 = ((const uint*)(h + (size_t)s5 * H))[t];
        uint u6 = ((const uint*)(h + (size_t)s6 * H))[t];
        uint u7 = ((const uint*)(h + (size_t)s7 * H))[t];
        float wa = dinv[s0] * dn, wb = dinv[s1] * dn, wc = dinv[s2] * dn, wd = dinv[s3] * dn;
        float we = dinv[s4] * dn, wf = dinv[s5] * dn, wg = dinv[s6] * dn, wh = dinv[s7] * dn;
        ax += bflo(u0) * wa + bflo(u1) * wb + bflo(u2) * wc + bflo(u3) * wd
            + bflo(u4) * we + bflo(u5) * wf + bflo(u6) * wg + bflo(u7) * wh;
        ay += bfhi(u0) * wa + bfhi(u1) * wb + bfhi(u2) * wc + bfhi(u3) * wd
            + bfhi(u4) * we + bfhi(u5) * wf + bfhi(u6) * wg + bfhi(u7) * wh;
    }
    for (; i < hi; ++i) {
        int s0 = csr2[i].x & 0xffff;
        uint u0 = ((const uint*)(h + (size_t)s0 * H))[t];
        float wa = dinv[s0] * dn;
        ax += bflo(u0) * wa;
        ay += bfhi(u0) * wa;
    }
    float2 bb = ((const float2*)bias)[t];
    float2 r;
    r.x = fmaxf(ax + bb.x, 0.f);
    r.y = fmaxf(ay + bb.y, 0.f);
    ((float2*)p)[(size_t)n * (H / 2) + t] = r;
}

// Y[.,128](bf16) = X[.,128](f32) @ W[128][128]; 32 rows / 256-thread block.
#define GNT 32
__global__ __launch_bounds__(256) void k_gemm128(const float* __restrict__ X,
                                                 const float* __restrict__ W,
                                                 ushort* __restrict__ Y) {
    __shared__ float Ws[128 * 128];
    int t = threadIdx.x;
    int base = blockIdx.x * GNT;
    for (int i = t * 4; i < 128 * 128; i += 256 * 4)
        *(float4*)&Ws[i] = *(const float4*)&W[i];
    __syncthreads();
    int jt = (t & 31) * 4;        // 4 output cols
    int nt = (t >> 5) * 4;        // 4 local rows
    float4 a0 = {0,0,0,0}, a1 = {0,0,0,0}, a2 = {0,0,0,0}, a3 = {0,0,0,0};
    const float* x0 = X + (size_t)(base + nt + 0) * H;
    const float* x1 = X + (size_t)(base + nt + 1) * H;
    const float* x2 = X + (size_t)(base + nt + 2) * H;
    const float* x3 = X + (size_t)(base + nt + 3) * H;
    for (int k0 = 0; k0 < 128; k0 += 4) {
        float4 xv0 = *(const float4*)(x0 + k0);
        float4 xv1 = *(const float4*)(x1 + k0);
        float4 xv2 = *(const float4*)(x2 + k0);
        float4 xv3 = *(const float4*)(x3 + k0);
#pragma unroll
        for (int kk = 0; kk < 4; ++kk) {
            float4 w = *(float4*)&Ws[(k0 + kk) * 128 + jt];
            float v0 = (&xv0.x)[kk], v1 = (&xv1.x)[kk], v2 = (&xv2.x)[kk], v3 = (&xv3.x)[kk];
            a0.x += v0 * w.x; a0.y += v0 * w.y; a0.z += v0 * w.z; a0.w += v0 * w.w;
            a1.x += v1 * w.x; a1.y += v1 * w.y; a1.z += v1 * w.z; a1.w += v1 * w.w;
            a2.x += v2 * w.x; a2.y += v2 * w.y; a2.z += v2 * w.z; a2.w += v2 * w.w;
            a3.x += v3 * w.x; a3.y += v3 * w.y; a3.z += v3 * w.z; a3.w += v3 * w.w;
        }
    }
    ushort4x o;
    if (base + nt + 0 < NN) {
        o.a = f2bf(a0.x); o.b = f2bf(a0.y); o.c = f2bf(a0.z); o.d = f2bf(a0.w);
        *(ushort4x*)&Y[(size_t)(base + nt + 0) * H + jt] = o;
    }
    if (base + nt + 1 < NN) {
        o.a = f2bf(a1.x); o.b = f2bf(a1.y); o.c = f2bf(a1.z); o.d = f2bf(a1.w);
        *(ushort4x*)&Y[(size_t)(base + nt + 1) * H + jt] = o;
    }
    if (base + nt + 2 < NN) {
        o.a = f2bf(a2.x); o.b = f2bf(a2.y); o.c = f2bf(a2.z); o.d = f2bf(a2.w);
        *(ushort4x*)&Y[(size_t)(base + nt + 2) * H + jt] = o;
    }
    if (base + nt + 3 < NN) {
        o.a = f2bf(a3.x); o.b = f2bf(a3.y); o.c = f2bf(a3.z); o.d = f2bf(a3.w);
        *(ushort4x*)&Y[(size_t)(base + nt + 3) * H + jt] = o;
    }
}

// Edge-parallel fused edge stage: 16-lane group per CSR entry, 4 entries/group,
// all 8 row-loads issued before compute (8 outstanding loads/lane).
#define EPB 64   // csr entries per 256-thread block
__global__ __launch_bounds__(256) void k_edge(const int2* __restrict__ csr2,
                                              const ushort* __restrict__ u,
                                              const ushort* __restrict__ v,
                                              const float* __restrict__ bl1,
                                              const float* __restrict__ Wl2,
                                              const float* __restrict__ bl2,
                                              float* __restrict__ out) {
    int g = threadIdx.x >> 4;          // group 0..15
    int l16 = threadIdx.x & 15;
    int base = blockIdx.x * EPB + g;

    float4 ba = *(const float4*)(bl1 + l16 * 8);
    float4 bb = *(const float4*)(bl1 + l16 * 8 + 4);
    float4 w0 = *(const float4*)(Wl2 + l16 * 16);
    float4 w1 = *(const float4*)(Wl2 + l16 * 16 + 4);
    float4 w2 = *(const float4*)(Wl2 + l16 * 16 + 8);
    float4 w3 = *(const float4*)(Wl2 + l16 * 16 + 12);
    float b20 = bl2[0], b21 = bl2[1];

    int2 e0 = csr2[base];
    int2 e1 = csr2[base + 16];
    int2 e2 = csr2[base + 32];
    int2 e3 = csr2[base + 48];
    uint4 uu0 = *(const uint4*)((const uint*)(u + (size_t)((uint)e0.x & 0xffffu) * H) + l16 * 4);
    uint4 vv0 = *(const uint4*)((const uint*)(v + (size_t)((uint)e0.x >> 16) * H) + l16 * 4);
    uint4 uu1 = *(const uint4*)((const uint*)(u + (size_t)((uint)e1.x & 0xffffu) * H) + l16 * 4);
    uint4 vv1 = *(const uint4*)((const uint*)(v + (size_t)((uint)e1.x >> 16) * H) + l16 * 4);
    uint4 uu2 = *(const uint4*)((const uint*)(u + (size_t)((uint)e2.x & 0xffffu) * H) + l16 * 4);
    uint4 vv2 = *(const uint4*)((const uint*)(v + (size_t)((uint)e2.x >> 16) * H) + l16 * 4);
    uint4 uu3 = *(const uint4*)((const uint*)(u + (size_t)((uint)e3.x & 0xffffu) * H) + l16 * 4);
    uint4 vv3 = *(const uint4*)((const uint*)(v + (size_t)((uint)e3.x >> 16) * H) + l16 * 4);

#pragma unroll
    for (int q = 0; q < 4; ++q) {
        uint4 uu = (q == 0) ? uu0 : (q == 1) ? uu1 : (q == 2) ? uu2 : uu3;
        uint4 vv = (q == 0) ? vv0 : (q == 1) ? vv1 : (q == 2) ? vv2 : vv3;
        int eid = (q == 0) ? e0.y : (q == 1) ? e1.y : (q == 2) ? e2.y : e3.y;
        float h0 = fmaxf(bflo(uu.x) + bflo(vv.x) + ba.x, 0.f);
        float h1 = fmaxf(bfhi(uu.x) + bfhi(vv.x) + ba.y, 0.f);
        float h2 = fmaxf(bflo(uu.y) + bflo(vv.y) + ba.z, 0.f);
        float h3 = fmaxf(bfhi(uu.y) + bfhi(vv.y) + ba.w, 0.f);
        float h4 = fmaxf(bflo(uu.z) + bflo(vv.z) + bb.x, 0.f);
        float h5 = fmaxf(bfhi(uu.z) + bfhi(vv.z) + bb.y, 0.f);
        float h6 = fmaxf(bflo(uu.w) + bflo(vv.w) + bb.z, 0.f);
        float h7 = fmaxf(bfhi(uu.w) + bfhi(vv.w) + bb.w, 0.f);
        float p0 = h0 * w0.x + h1 * w0.z + h2 * w1.x + h3 * w1.z
                 + h4 * w2.x + h5 * w2.z + h6 * w3.x + h7 * w3.z;
        float p1 = h0 * w0.y + h1 * w0.w + h2 * w1.y + h3 * w1.w
                 + h4 * w2.y + h5 * w2.w + h6 * w3.y + h7 * w3.w;
#pragma unroll
        for (int m = 1; m < 16; m <<= 1) {
            p0 += __shfl_xor(p0, m, 64);
            p1 += __shfl_xor(p1, m, 64);
        }
        if (l16 == 0) {
            float2 o;
            o.x = fmaxf(p0 + b20, 0.f);
            o.y = fmaxf(p1 + b21, 0.f);
            *(float2*)(out + (size_t)eid * 2) = o;
        }
    }
}

extern "C" void kernel_launch(void* const* d_in, const int* in_sizes, int n_in,
                              void* d_out, int out_size, void* d_ws, size_t ws_size,
                              hipStream_t stream) {
    const float* x   = (const float*)d_in[0];
    const float* W1  = (const float*)d_in[1];
    const float* b1  = (const float*)d_in[2];
    const float* W2  = (const float*)d_in[3];
    const float* b2  = (const float*)d_in[4];
    const float* Wl1 = (const float*)d_in[5];
    const float* bl1 = (const float*)d_in[6];
    const float* Wl2 = (const float*)d_in[7];
    const float* bl2 = (const float*)d_in[8];
    const int*   ei  = (const int*)d_in[9];
    const int* src = ei;
    const int* dst = ei + NE;
    float* out = (float*)d_out;

    char* ws = (char*)d_ws;
    size_t off = 0;
    auto alloc = [&](size_t bytes) -> void* {
        void* p = ws + off;
        off = (off + bytes + 255) & ~(size_t)255;
        return p;
    };
    const size_t NP = 50048;  // padded rows (gemm tile over-read safety)
    int*    indeg    = (int*)alloc(NN * 4);
    float*  dinv     = (float*)alloc(NN * 4);
    int*    rowstart = (int*)alloc((NN + 1) * 4);
    int*    bsum     = (int*)alloc(256 * 4);
    int*    boff     = (int*)alloc(256 * 4);
    int*    Hg       = (int*)alloc((size_t)NBE * NB * 4);
    int*    Offb     = (int*)alloc((size_t)NBE * NB * 4);
    int2*   csr2     = (int2*)alloc((size_t)NE * 8);
    float*  pf       = (float*)alloc(NP * H * 4);    // p1 then p2 (f32); bin aliases this
    ushort* hbf      = (ushort*)alloc(NP * H * 2);   // h1 then h2 (bf16)
    ushort* ubf      = (ushort*)alloc(NP * H * 2);
    ushort* vbf      = (ushort*)alloc(NP * H * 2);
    int2*   bin      = (int2*)pf;  // 6.4MB, dead before first k_agg writes pf

    k_zero1<<<(NN + 255) / 256, 256, 0, stream>>>(indeg, NN);
    k_indeg<<<(NE + 255) / 256, 256, 0, stream>>>(dst, indeg);
    k_dinv<<<(NN + 255) / 256, 256, 0, stream>>>(indeg, dinv);
    k_bsum<<<SCAN_NBLK, 256, 0, stream>>>(indeg, bsum);
    k_bscan<<<1, 256, 0, stream>>>(bsum, boff);
    k_rowstart<<<SCAN_NBLK, 256, 0, stream>>>(indeg, boff, rowstart);
    k_hist<<<NBE, 512, 0, stream>>>(dst, Hg);
    k_hscan<<<1, 512, 0, stream>>>(rowstart, Hg, Offb);
    k_scatter<<<NBE, 512, 0, stream>>>(src, dst, Offb, bin);
    k_binB<<<NB, 256, 0, stream>>>(rowstart, bin, csr2);

    k_xw1<<<NN / 2, 256, 0, stream>>>(x, W1, hbf);                        // h1
    k_agg<<<NN / 4, 256, 0, stream>>>(hbf, dinv, rowstart, csr2, b1, pf); // p1
    k_gemm128<<<(NN + GNT - 1) / GNT, 256, 0, stream>>>(pf, W2, hbf);     // h2
    k_agg<<<NN / 4, 256, 0, stream>>>(hbf, dinv, rowstart, csr2, b2, pf); // p2
    k_gemm128<<<(NN + GNT - 1) / GNT, 256, 0, stream>>>(pf, Wl1, ubf);            // u
    k_gemm128<<<(NN + GNT - 1) / GNT, 256, 0, stream>>>(pf, Wl1 + 128 * H, vbf);  // v
    k_edge<<<NE / EPB, 256, 0, stream>>>(csr2, ubf, vbf, bl1, Wl2, bl2, out);
}

// Round 9
// 245.451 us; speedup vs baseline: 1.6494x; 1.3725x over previous
//
#include <hip/hip_runtime.h>

#define NN 50000
#define NE 800000
#define F_IN 8
#define H 128
#define SCAN_NBLK ((NN + 255) / 256)   // 196
#define BSH 7
#define NB ((NN + 127) >> BSH)         // 391 buckets, 128 dsts each
#define EBLK 4096
#define NBE ((NE + EBLK - 1) / EBLK)   // 196 edge blocks
#define NP 50048                       // padded rows; 50048 = 391*128 exactly

typedef unsigned int uint;
typedef unsigned short ushort;
typedef __attribute__((ext_vector_type(8))) short short8v;
typedef __attribute__((ext_vector_type(4))) float f32x4;

__device__ __forceinline__ ushort f2bf(float f) {
    uint u = __float_as_uint(f);
    uint r = (u + 0x7fffu + ((u >> 16) & 1u)) >> 16;
    return (ushort)r;
}
__device__ __forceinline__ float bflo(uint u) { return __uint_as_float(u << 16); }
__device__ __forceinline__ float bfhi(uint u) { return __uint_as_float(u & 0xffff0000u); }

__global__ void k_zero1(int* __restrict__ a, int n) {
    int i = blockIdx.x * blockDim.x + threadIdx.x;
    if (i < n) a[i] = 0;
}

__global__ void k_indeg(const int* __restrict__ dst, int* __restrict__ indeg) {
    int i = blockIdx.x * blockDim.x + threadIdx.x;
    if (i < NE) atomicAdd(&indeg[dst[i]], 1);
}

__global__ void k_dinv(const int* __restrict__ indeg, float* __restrict__ dinv) {
    int i = blockIdx.x * blockDim.x + threadIdx.x;
    if (i < NN) dinv[i] = rsqrtf((float)(indeg[i] + 1));
}

// ---- multi-block exclusive scan of indeg -> rowstart ----
__global__ __launch_bounds__(256) void k_bsum(const int* __restrict__ indeg,
                                              int* __restrict__ bsum) {
    int b = blockIdx.x;
    int i = b * 256 + threadIdx.x;
    int v = (i < NN) ? indeg[i] : 0;
#pragma unroll
    for (int m = 1; m < 64; m <<= 1) v += __shfl_xor(v, m, 64);
    __shared__ int ws[4];
    if ((threadIdx.x & 63) == 0) ws[threadIdx.x >> 6] = v;
    __syncthreads();
    if (threadIdx.x == 0) bsum[b] = ws[0] + ws[1] + ws[2] + ws[3];
}

__global__ __launch_bounds__(256) void k_bscan(const int* __restrict__ bsum,
                                               int* __restrict__ boff) {
    __shared__ int s[256];
    int t = threadIdx.x;
    s[t] = (t < SCAN_NBLK) ? bsum[t] : 0;
    __syncthreads();
    for (int off = 1; off < 256; off <<= 1) {
        int u = (t >= off) ? s[t - off] : 0;
        __syncthreads();
        s[t] += u;
        __syncthreads();
    }
    boff[t] = (t == 0) ? 0 : s[t - 1];
}

__global__ __launch_bounds__(256) void k_rowstart(const int* __restrict__ indeg,
                                                  const int* __restrict__ boff,
                                                  int* __restrict__ rowstart) {
    int b = blockIdx.x, t = threadIdx.x;
    int i = b * 256 + t;
    int v = (i < NN) ? indeg[i] : 0;
    __shared__ int s[256];
    s[t] = v;
    __syncthreads();
    for (int off = 1; off < 256; off <<= 1) {
        int u = (t >= off) ? s[t - off] : 0;
        __syncthreads();
        s[t] += u;
        __syncthreads();
    }
    if (i < NN) rowstart[i] = boff[b] + s[t] - v;
    if (i == NN - 1) rowstart[NN] = NE;
}

// ---- deterministic two-phase counting scatter into coarse buckets ----
__global__ __launch_bounds__(512) void k_hist(const int* __restrict__ dst,
                                              int* __restrict__ Hg) {
    __shared__ int h[NB];
    int t = threadIdx.x, blk = blockIdx.x;
    for (int b = t; b < NB; b += 512) h[b] = 0;
    __syncthreads();
    int e0 = blk * EBLK;
    int e1 = e0 + EBLK; if (e1 > NE) e1 = NE;
    for (int i = e0 + t; i < e1; i += 512) atomicAdd(&h[dst[i] >> BSH], 1);
    __syncthreads();
    for (int b = t; b < NB; b += 512) Hg[blk * NB + b] = h[b];
}

__global__ __launch_bounds__(512) void k_hscan(const int* __restrict__ rowstart,
                                               const int* __restrict__ Hg,
                                               int* __restrict__ Off) {
    int t = threadIdx.x;
    if (t >= NB) return;
    int run = rowstart[t << BSH];
    for (int e = 0; e < NBE; ++e) {
        int c = Hg[e * NB + t];
        Off[e * NB + t] = run;
        run += c;
    }
}

__global__ __launch_bounds__(512) void k_scatter(const int* __restrict__ src,
                                                 const int* __restrict__ dst,
                                                 const int* __restrict__ Off,
                                                 int2* __restrict__ bin) {
    __shared__ int cur[NB];
    int t = threadIdx.x, blk = blockIdx.x;
    for (int b = t; b < NB; b += 512) cur[b] = Off[blk * NB + b];
    __syncthreads();
    int e0 = blk * EBLK;
    int e1 = e0 + EBLK; if (e1 > NE) e1 = NE;
    for (int i = e0 + t; i < e1; i += 512) {
        int d = dst[i];
        int b = d >> BSH;
        int pos = atomicAdd(&cur[b], 1);
        bin[pos] = make_int2((src[i] & 0xffff) | ((d & ((1 << BSH) - 1)) << 16), i);
    }
}

// Bucket -> per-dst CSR. csr2.x packs (src | dst<<16) [uint math]; csr2.y = edge id.
__global__ __launch_bounds__(256) void k_binB(const int* __restrict__ rowstart,
                                              const int2* __restrict__ bin,
                                              int2* __restrict__ csr2) {
    int b = blockIdx.x, t = threadIdx.x;
    __shared__ int cur[1 << BSH];
    __shared__ int rs[1 << BSH];
    if (t < (1 << BSH)) {
        cur[t] = 0;
        int n = (b << BSH) + t;
        rs[t] = (n < NN) ? rowstart[n] : NE;
    }
    __syncthreads();
    int base = rowstart[b << BSH];
    int nend = (b + 1) << BSH;
    int end = rowstart[(nend < NN) ? nend : NN];
    for (int idx = base + t; idx < end; idx += 256) {
        int2 e = bin[idx];
        int ld = (int)((uint)e.x >> 16);
        uint d = (uint)((b << BSH) + ld);
        int pos = atomicAdd(&cur[ld], 1);
        csr2[rs[ld] + pos] = make_int2((int)(((uint)e.x & 0xffffu) | (d << 16)), e.y);
    }
}

// Convert W2 / Wl1(top,bot) to bf16 transposed: Wt[c*128 + k] = W[k][c]
__global__ __launch_bounds__(256) void k_wcvt(const float* __restrict__ W2,
                                              const float* __restrict__ Wl1,
                                              ushort* __restrict__ Wt2,
                                              ushort* __restrict__ Wtu,
                                              ushort* __restrict__ Wtv) {
    int id = blockIdx.x * 256 + threadIdx.x;   // 3*16384 total
    int m = id >> 14;
    int r = id & 16383;
    int c = r >> 7, k = r & 127;
    float v;
    ushort* dstp;
    if (m == 0)      { v = W2[k * 128 + c];          dstp = Wt2; }
    else if (m == 1) { v = Wl1[k * 128 + c];         dstp = Wtu; }
    else             { v = Wl1[(128 + k) * 128 + c]; dstp = Wtv; }
    dstp[r] = f2bf(v);
}

// h[n][j] = sum_k x[n][k] * W1[k][j], bf16 output  (2 nodes / 256-thread block)
__global__ __launch_bounds__(256) void k_xw1(const float* __restrict__ x,
                                             const float* __restrict__ W1,
                                             ushort* __restrict__ h) {
    int t = threadIdx.x;
    int n = blockIdx.x * 2 + (t >> 7);
    int j = t & 127;
    const float* xr = x + n * F_IN;
    float acc = 0.f;
#pragma unroll
    for (int k = 0; k < F_IN; ++k) acc += xr[k] * W1[k * H + j];
    h[n * H + j] = f2bf(acc);
}

// p[n] = relu( h[n]*dinv[n]^2 + sum_{incoming s} h[s]*dinv[s]*dinv[n] + bias )
// OUTPUT NOW bf16 (packed uint). 4 nodes/256-thr block; edge loop unrolled x8.
__global__ __launch_bounds__(256) void k_agg(const ushort* __restrict__ h,
                                             const float* __restrict__ dinv,
                                             const int* __restrict__ rowstart,
                                             const int2* __restrict__ csr2,
                                             const float* __restrict__ bias,
                                             uint* __restrict__ p) {
    int n = blockIdx.x * 4 + (threadIdx.x >> 6);
    int t = threadIdx.x & 63;
    float dn = dinv[n];
    uint us = ((const uint*)(h + (size_t)n * H))[t];
    float w0 = dn * dn;
    float ax = bflo(us) * w0;
    float ay = bfhi(us) * w0;
    int lo = rowstart[n], hi = rowstart[n + 1];
    int i = lo;
    for (; i + 7 < hi; i += 8) {
        int s0 = csr2[i + 0].x & 0xffff;
        int s1 = csr2[i + 1].x & 0xffff;
        int s2 = csr2[i + 2].x & 0xffff;
        int s3 = csr2[i + 3].x & 0xffff;
        int s4 = csr2[i + 4].x & 0xffff;
        int s5 = csr2[i + 5].x & 0xffff;
        int s6 = csr2[i + 6].x & 0xffff;
        int s7 = csr2[i + 7].x & 0xffff;
        uint u0 = ((const uint*)(h + (size_t)s0 * H))[t];
        uint u1 = ((const uint*)(h + (size_t)s1 * H))[t];
        uint u2 = ((const uint*)(h + (size_t)s2 * H))[t];
        uint u3 = ((const uint*)(h + (size_t)s3 * H))[t];
        uint u4 = ((const uint*)(h + (size_t)s4 * H))[t];
        uint u5 = ((const uint*)(h + (size_t)s5 * H))[t];
        uint u6 = ((const uint*)(h + (size_t)s6 * H))[t];
        uint u7 = ((const uint*)(h + (size_t)s7 * H))[t];
        float wa = dinv[s0] * dn, wb = dinv[s1] * dn, wc = dinv[s2] * dn, wd = dinv[s3] * dn;
        float we = dinv[s4] * dn, wf = dinv[s5] * dn, wg = dinv[s6] * dn, wh = dinv[s7] * dn;
        ax += bflo(u0) * wa + bflo(u1) * wb + bflo(u2) * wc + bflo(u3) * wd
            + bflo(u4) * we + bflo(u5) * wf + bflo(u6) * wg + bflo(u7) * wh;
        ay += bfhi(u0) * wa + bfhi(u1) * wb + bfhi(u2) * wc + bfhi(u3) * wd
            + bfhi(u4) * we + bfhi(u5) * wf + bfhi(u6) * wg + bfhi(u7) * wh;
    }
    for (; i < hi; ++i) {
        int s0 = csr2[i].x & 0xffff;
        uint u0 = ((const uint*)(h + (size_t)s0 * H))[t];
        float wa = dinv[s0] * dn;
        ax += bflo(u0) * wa;
        ay += bfhi(u0) * wa;
    }
    float2 bb = ((const float2*)bias)[t];
    ushort rx = f2bf(fmaxf(ax + bb.x, 0.f));
    ushort ry = f2bf(fmaxf(ay + bb.y, 0.f));
    p[(size_t)n * 64 + t] = (uint)rx | ((uint)ry << 16);
}

// MFMA bf16 GEMM: Y[NP][128] = X[NP][128] @ W  (W given transposed: Wt[c][k]).
// 4 waves/block, 32 rows/wave, 128 rows/block, grid = NP/128 = 391.
// Wt staged in 32KB LDS, XOR-swizzled (byte ^= (c&7)<<4) on write AND read.
__global__ __launch_bounds__(256) void k_gmm(const ushort* __restrict__ Xb,
                                             const ushort* __restrict__ Wt,
                                             ushort* __restrict__ Y) {
    __shared__ ushort Ws[16384];
    int t = threadIdx.x;
    // stage 32768 bytes = 2048 x 16B chunks
    for (int i = t; i < 2048; i += 256) {
        int o = i * 16;
        int phys = o ^ (((o >> 8) & 7) << 4);
        *(uint4*)((char*)Ws + phys) = *(const uint4*)((const char*)Wt + o);
    }
    __syncthreads();

    int lane = t & 63;
    int kg = lane >> 4;          // k-group 0..3 (8 bf16 each)
    int lr = lane & 15;          // row-within-strip / col-within-tile
    int row0 = blockIdx.x * 128 + (t >> 6) * 32;

    // A fragments: 2 strips x 4 k-chunks, 16B contiguous per lane
    short8v a[2][4];
#pragma unroll
    for (int s = 0; s < 2; ++s)
#pragma unroll
        for (int kk = 0; kk < 4; ++kk)
            a[s][kk] = *(const short8v*)((const char*)Xb +
                ((size_t)(row0 + s * 16 + lr) * 128 + kk * 32 + kg * 8) * 2);

#pragma unroll
    for (int ct = 0; ct < 8; ++ct) {
        int c = ct * 16 + lr;
        f32x4 acc0 = {0.f, 0.f, 0.f, 0.f};
        f32x4 acc1 = {0.f, 0.f, 0.f, 0.f};
#pragma unroll
        for (int kk = 0; kk < 4; ++kk) {
            int o = c * 256 + kk * 64 + kg * 16;
            int phys = o ^ ((c & 7) << 4);
            short8v b = *(const short8v*)((const char*)Ws + phys);
            acc0 = __builtin_amdgcn_mfma_f32_16x16x32_bf16(a[0][kk], b, acc0, 0, 0, 0);
            acc1 = __builtin_amdgcn_mfma_f32_16x16x32_bf16(a[1][kk], b, acc1, 0, 0, 0);
        }
        // C/D: col = lane&15, row = (lane>>4)*4 + r   [m89-verified]
        int colo = ct * 16 + lr;
#pragma unroll
        for (int r = 0; r < 4; ++r) {
            Y[(size_t)(row0 + kg * 4 + r) * 128 + colo] = f2bf(acc0[r]);
            Y[(size_t)(row0 + 16 + kg * 4 + r) * 128 + colo] = f2bf(acc1[r]);
        }
    }
}

// Edge-parallel fused edge stage: 16-lane group per CSR entry, 4 entries/group.
#define EPB 64
__global__ __launch_bounds__(256) void k_edge(const int2* __restrict__ csr2,
                                              const ushort* __restrict__ u,
                                              const ushort* __restrict__ v,
                                              const float* __restrict__ bl1,
                                              const float* __restrict__ Wl2,
                                              const float* __restrict__ bl2,
                                              float* __restrict__ out) {
    int g = threadIdx.x >> 4;
    int l16 = threadIdx.x & 15;
    int base = blockIdx.x * EPB + g;

    float4 ba = *(const float4*)(bl1 + l16 * 8);
    float4 bb = *(const float4*)(bl1 + l16 * 8 + 4);
    float4 w0 = *(const float4*)(Wl2 + l16 * 16);
    float4 w1 = *(const float4*)(Wl2 + l16 * 16 + 4);
    float4 w2 = *(const float4*)(Wl2 + l16 * 16 + 8);
    float4 w3 = *(const float4*)(Wl2 + l16 * 16 + 12);
    float b20 = bl2[0], b21 = bl2[1];

    int2 e0 = csr2[base];
    int2 e1 = csr2[base + 16];
    int2 e2 = csr2[base + 32];
    int2 e3 = csr2[base + 48];
    uint4 uu0 = *(const uint4*)((const uint*)(u + (size_t)((uint)e0.x & 0xffffu) * H) + l16 * 4);
    uint4 vv0 = *(const uint4*)((const uint*)(v + (size_t)((uint)e0.x >> 16) * H) + l16 * 4);
    uint4 uu1 = *(const uint4*)((const uint*)(u + (size_t)((uint)e1.x & 0xffffu) * H) + l16 * 4);
    uint4 vv1 = *(const uint4*)((const uint*)(v + (size_t)((uint)e1.x >> 16) * H) + l16 * 4);
    uint4 uu2 = *(const uint4*)((const uint*)(u + (size_t)((uint)e2.x & 0xffffu) * H) + l16 * 4);
    uint4 vv2 = *(const uint4*)((const uint*)(v + (size_t)((uint)e2.x >> 16) * H) + l16 * 4);
    uint4 uu3 = *(const uint4*)((const uint*)(u + (size_t)((uint)e3.x & 0xffffu) * H) + l16 * 4);
    uint4 vv3 = *(const uint4*)((const uint*)(v + (size_t)((uint)e3.x >> 16) * H) + l16 * 4);

#pragma unroll
    for (int q = 0; q < 4; ++q) {
        uint4 uu = (q == 0) ? uu0 : (q == 1) ? uu1 : (q == 2) ? uu2 : uu3;
        uint4 vv = (q == 0) ? vv0 : (q == 1) ? vv1 : (q == 2) ? vv2 : vv3;
        int eid = (q == 0) ? e0.y : (q == 1) ? e1.y : (q == 2) ? e2.y : e3.y;
        float h0 = fmaxf(bflo(uu.x) + bflo(vv.x) + ba.x, 0.f);
        float h1 = fmaxf(bfhi(uu.x) + bfhi(vv.x) + ba.y, 0.f);
        float h2 = fmaxf(bflo(uu.y) + bflo(vv.y) + ba.z, 0.f);
        float h3 = fmaxf(bfhi(uu.y) + bfhi(vv.y) + ba.w, 0.f);
        float h4 = fmaxf(bflo(uu.z) + bflo(vv.z) + bb.x, 0.f);
        float h5 = fmaxf(bfhi(uu.z) + bfhi(vv.z) + bb.y, 0.f);
        float h6 = fmaxf(bflo(uu.w) + bflo(vv.w) + bb.z, 0.f);
        float h7 = fmaxf(bfhi(uu.w) + bfhi(vv.w) + bb.w, 0.f);
        float p0 = h0 * w0.x + h1 * w0.z + h2 * w1.x + h3 * w1.z
                 + h4 * w2.x + h5 * w2.z + h6 * w3.x + h7 * w3.z;
        float p1 = h0 * w0.y + h1 * w0.w + h2 * w1.y + h3 * w1.w
                 + h4 * w2.y + h5 * w2.w + h6 * w3.y + h7 * w3.w;
#pragma unroll
        for (int m = 1; m < 16; m <<= 1) {
            p0 += __shfl_xor(p0, m, 64);
            p1 += __shfl_xor(p1, m, 64);
        }
        if (l16 == 0) {
            float2 o;
            o.x = fmaxf(p0 + b20, 0.f);
            o.y = fmaxf(p1 + b21, 0.f);
            *(float2*)(out + (size_t)eid * 2) = o;
        }
    }
}

extern "C" void kernel_launch(void* const* d_in, const int* in_sizes, int n_in,
                              void* d_out, int out_size, void* d_ws, size_t ws_size,
                              hipStream_t stream) {
    const float* x   = (const float*)d_in[0];
    const float* W1  = (const float*)d_in[1];
    const float* b1  = (const float*)d_in[2];
    const float* W2  = (const float*)d_in[3];
    const float* b2  = (const float*)d_in[4];
    const float* Wl1 = (const float*)d_in[5];
    const float* bl1 = (const float*)d_in[6];
    const float* Wl2 = (const float*)d_in[7];
    const float* bl2 = (const float*)d_in[8];
    const int*   ei  = (const int*)d_in[9];
    const int* src = ei;
    const int* dst = ei + NE;
    float* out = (float*)d_out;

    char* ws = (char*)d_ws;
    size_t off = 0;
    auto alloc = [&](size_t bytes) -> void* {
        void* p = ws + off;
        off = (off + bytes + 255) & ~(size_t)255;
        return p;
    };
    int*    indeg    = (int*)alloc(NN * 4);
    float*  dinv     = (float*)alloc(NN * 4);
    int*    rowstart = (int*)alloc((NN + 1) * 4);
    int*    bsum     = (int*)alloc(256 * 4);
    int*    boff     = (int*)alloc(256 * 4);
    int*    Hg       = (int*)alloc((size_t)NBE * NB * 4);
    int*    Offb     = (int*)alloc((size_t)NBE * NB * 4);
    int2*   csr2     = (int2*)alloc((size_t)NE * 8);
    ushort* hbf      = (ushort*)alloc((size_t)NP * H * 2);   // h1 then h2
    ushort* pbf      = (ushort*)alloc((size_t)NP * H * 2);   // p1 then p2 (bf16)
    ushort* ubf      = (ushort*)alloc((size_t)NP * H * 2);
    ushort* vbf      = (ushort*)alloc((size_t)NP * H * 2);
    ushort* Wt2      = (ushort*)alloc(128 * 128 * 2);
    ushort* Wtu      = (ushort*)alloc(128 * 128 * 2);
    ushort* Wtv      = (ushort*)alloc(128 * 128 * 2);
    int2*   bin      = (int2*)ubf;  // 6.4MB alias; dead before gemm-u writes ubf

    k_zero1<<<(NN + 255) / 256, 256, 0, stream>>>(indeg, NN);
    k_indeg<<<(NE + 255) / 256, 256, 0, stream>>>(dst, indeg);
    k_dinv<<<(NN + 255) / 256, 256, 0, stream>>>(indeg, dinv);
    k_bsum<<<SCAN_NBLK, 256, 0, stream>>>(indeg, bsum);
    k_bscan<<<1, 256, 0, stream>>>(bsum, boff);
    k_rowstart<<<SCAN_NBLK, 256, 0, stream>>>(indeg, boff, rowstart);
    k_hist<<<NBE, 512, 0, stream>>>(dst, Hg);
    k_hscan<<<1, 512, 0, stream>>>(rowstart, Hg, Offb);
    k_scatter<<<NBE, 512, 0, stream>>>(src, dst, Offb, bin);
    k_binB<<<NB, 256, 0, stream>>>(rowstart, bin, csr2);
    k_wcvt<<<192, 256, 0, stream>>>(W2, Wl1, Wt2, Wtu, Wtv);

    k_xw1<<<NN / 2, 256, 0, stream>>>(x, W1, hbf);                              // h1
    k_agg<<<NN / 4, 256, 0, stream>>>(hbf, dinv, rowstart, csr2, b1, (uint*)pbf); // p1
    k_gmm<<<NP / 128, 256, 0, stream>>>(pbf, Wt2, hbf);                         // h2
    k_agg<<<NN / 4, 256, 0, stream>>>(hbf, dinv, rowstart, csr2, b2, (uint*)pbf); // p2
    k_gmm<<<NP / 128, 256, 0, stream>>>(pbf, Wtu, ubf);                         // u
    k_gmm<<<NP / 128, 256, 0, stream>>>(pbf, Wtv, vbf);                         // v
    k_edge<<<NE / EPB, 256, 0, stream>>>(csr2, ubf, vbf, bl1, Wl2, bl2, out);
}

// Round 10
// 205.810 us; speedup vs baseline: 1.9670x; 1.1926x over previous
//
#include <hip/hip_runtime.h>

#define NN 50000
#define NE 800000
#define F_IN 8
#define H 128
#define BSH 7
#define NB ((NN + 127) >> BSH)         // 391 buckets, 128 dsts each
#define EBLK 4096
#define NBE ((NE + EBLK - 1) / EBLK)   // 196 edge blocks
#define NP 50048                       // padded rows; 50048 = 391*128 exactly

typedef unsigned int uint;
typedef unsigned short ushort;
typedef __attribute__((ext_vector_type(8))) short short8v;
typedef __attribute__((ext_vector_type(4))) float f32x4;

__device__ __forceinline__ ushort f2bf(float f) {
    uint u = __float_as_uint(f);
    uint r = (u + 0x7fffu + ((u >> 16) & 1u)) >> 16;
    return (ushort)r;
}
__device__ __forceinline__ float bflo(uint u) { return __uint_as_float(u << 16); }
__device__ __forceinline__ float bfhi(uint u) { return __uint_as_float(u & 0xffff0000u); }

// ---- bucket histogram over edge blocks ----
__global__ __launch_bounds__(512) void k_hist(const int* __restrict__ dst,
                                              int* __restrict__ Hg) {
    __shared__ int h[NB];
    int t = threadIdx.x, blk = blockIdx.x;
    for (int b = t; b < NB; b += 512) h[b] = 0;
    __syncthreads();
    int e0 = blk * EBLK;
    int e1 = e0 + EBLK; if (e1 > NE) e1 = NE;
    for (int i = e0 + t; i < e1; i += 512) atomicAdd(&h[dst[i] >> BSH], 1);
    __syncthreads();
    for (int b = t; b < NB; b += 512) Hg[blk * NB + b] = h[b];
}

// ---- bucket bases: column-sum Hg then exclusive scan across buckets ----
__global__ __launch_bounds__(512) void k_bktscan(const int* __restrict__ Hg,
                                                 int* __restrict__ Bbase) {
    __shared__ int s[512];
    int t = threadIdx.x;
    int acc = 0;
    if (t < NB)
        for (int e = 0; e < NBE; ++e) acc += Hg[e * NB + t];
    s[t] = acc;
    __syncthreads();
    for (int off = 1; off < 512; off <<= 1) {
        int v = (t >= off) ? s[t - off] : 0;
        __syncthreads();
        s[t] += v;
        __syncthreads();
    }
    if (t <= NB) Bbase[t] = (t == 0) ? 0 : s[t - 1];
}

// ---- per-(edge-block,bucket) start offsets ----
__global__ __launch_bounds__(512) void k_hscan(const int* __restrict__ Bbase,
                                               const int* __restrict__ Hg,
                                               int* __restrict__ Off) {
    int t = threadIdx.x;
    if (t >= NB) return;
    int run = Bbase[t];
    for (int e = 0; e < NBE; ++e) {
        int c = Hg[e * NB + t];
        Off[e * NB + t] = run;
        run += c;
    }
}

// ---- deterministic scatter into bucket-contiguous regions ----
__global__ __launch_bounds__(512) void k_scatter(const int* __restrict__ src,
                                                 const int* __restrict__ dst,
                                                 const int* __restrict__ Off,
                                                 int2* __restrict__ bin) {
    __shared__ int cur[NB];
    int t = threadIdx.x, blk = blockIdx.x;
    for (int b = t; b < NB; b += 512) cur[b] = Off[blk * NB + b];
    __syncthreads();
    int e0 = blk * EBLK;
    int e1 = e0 + EBLK; if (e1 > NE) e1 = NE;
    for (int i = e0 + t; i < e1; i += 512) {
        int d = dst[i];
        int b = d >> BSH;
        int pos = atomicAdd(&cur[b], 1);
        bin[pos] = make_int2((src[i] & 0xffff) | ((d & ((1 << BSH) - 1)) << 16), i);
    }
}

// ---- bucket -> per-dst CSR; also derives rowstart + dinv (no global counting pass) ----
__global__ __launch_bounds__(256) void k_binB(const int* __restrict__ Bbase,
                                              const int2* __restrict__ bin,
                                              int2* __restrict__ csr2,
                                              int* __restrict__ rowstart,
                                              float* __restrict__ dinv) {
    int b = blockIdx.x, t = threadIdx.x;
    __shared__ int cnt[128];
    __shared__ int cur[128];
    int base = Bbase[b];
    int end = Bbase[b + 1];
    if (t < 128) cnt[t] = 0;
    __syncthreads();
    for (int idx = base + t; idx < end; idx += 256)
        atomicAdd(&cnt[(uint)bin[idx].x >> 16], 1);
    __syncthreads();
    int myc = (t < 128) ? cnt[t] : 0;
    // inclusive scan over 128 in LDS
    for (int off = 1; off < 128; off <<= 1) {
        int v = (t >= off && t < 128) ? cnt[t - off] : 0;
        __syncthreads();
        if (t < 128) cnt[t] += v;
        __syncthreads();
    }
    if (t < 128) {
        int startpos = base + cnt[t] - myc;   // exclusive
        int n = (b << BSH) + t;
        if (n < NN) {
            rowstart[n] = startpos;
            dinv[n] = rsqrtf((float)(myc + 1));
        }
        if (b == NB - 1 && t == 127) rowstart[NN] = NE;
        cur[t] = startpos;
    }
    __syncthreads();
    for (int idx = base + t; idx < end; idx += 256) {
        int2 e = bin[idx];
        int ld = (int)((uint)e.x >> 16);
        uint d = (uint)((b << BSH) + ld);
        int pos = atomicAdd(&cur[ld], 1);
        csr2[pos] = make_int2((int)(((uint)e.x & 0xffffu) | (d << 16)), e.y);
    }
}

// Convert W2 / Wl1(top,bot) to bf16 transposed: Wt[c*128 + k] = W[k][c]
__global__ __launch_bounds__(256) void k_wcvt(const float* __restrict__ W2,
                                              const float* __restrict__ Wl1,
                                              ushort* __restrict__ Wt2,
                                              ushort* __restrict__ Wtu,
                                              ushort* __restrict__ Wtv) {
    int id = blockIdx.x * 256 + threadIdx.x;   // 3*16384 total
    int m = id >> 14;
    int r = id & 16383;
    int c = r >> 7, k = r & 127;
    float v;
    ushort* dstp;
    if (m == 0)      { v = W2[k * 128 + c];          dstp = Wt2; }
    else if (m == 1) { v = Wl1[k * 128 + c];         dstp = Wtu; }
    else             { v = Wl1[(128 + k) * 128 + c]; dstp = Wtv; }
    dstp[r] = f2bf(v);
}

// h[n][j] = sum_k x[n][k] * W1[k][j], bf16 output  (2 nodes / 256-thread block)
__global__ __launch_bounds__(256) void k_xw1(const float* __restrict__ x,
                                             const float* __restrict__ W1,
                                             ushort* __restrict__ h) {
    int t = threadIdx.x;
    int n = blockIdx.x * 2 + (t >> 7);
    int j = t & 127;
    const float* xr = x + n * F_IN;
    float acc = 0.f;
#pragma unroll
    for (int k = 0; k < F_IN; ++k) acc += xr[k] * W1[k * H + j];
    h[n * H + j] = f2bf(acc);
}

// p[n] = relu( h[n]*dinv[n]^2 + sum_{incoming s} h[s]*dinv[s]*dinv[n] + bias )
// bf16 output (packed uint). 4 nodes/256-thr block; edge loop unrolled x8.
__global__ __launch_bounds__(256) void k_agg(const ushort* __restrict__ h,
                                             const float* __restrict__ dinv,
                                             const int* __restrict__ rowstart,
                                             const int2* __restrict__ csr2,
                                             const float* __restrict__ bias,
                                             uint* __restrict__ p) {
    int n = blockIdx.x * 4 + (threadIdx.x >> 6);
    int t = threadIdx.x & 63;
    float dn = dinv[n];
    uint us = ((const uint*)(h + (size_t)n * H))[t];
    float w0 = dn * dn;
    float ax = bflo(us) * w0;
    float ay = bfhi(us) * w0;
    int lo = rowstart[n], hi = rowstart[n + 1];
    int i = lo;
    for (; i + 7 < hi; i += 8) {
        int s0 = csr2[i + 0].x & 0xffff;
        int s1 = csr2[i + 1].x & 0xffff;
        int s2 = csr2[i + 2].x & 0xffff;
        int s3 = csr2[i + 3].x & 0xffff;
        int s4 = csr2[i + 4].x & 0xffff;
        int s5 = csr2[i + 5].x & 0xffff;
        int s6 = csr2[i + 6].x & 0xffff;
        int s7 = csr2[i + 7].x & 0xffff;
        uint u0 = ((const uint*)(h + (size_t)s0 * H))[t];
        uint u1 = ((const uint*)(h + (size_t)s1 * H))[t];
        uint u2 = ((const uint*)(h + (size_t)s2 * H))[t];
        uint u3 = ((const uint*)(h + (size_t)s3 * H))[t];
        uint u4 = ((const uint*)(h + (size_t)s4 * H))[t];
        uint u5 = ((const uint*)(h + (size_t)s5 * H))[t];
        uint u6 = ((const uint*)(h + (size_t)s6 * H))[t];
        uint u7 = ((const uint*)(h + (size_t)s7 * H))[t];
        float wa = dinv[s0] * dn, wb = dinv[s1] * dn, wc = dinv[s2] * dn, wd = dinv[s3] * dn;
        float we = dinv[s4] * dn, wf = dinv[s5] * dn, wg = dinv[s6] * dn, wh = dinv[s7] * dn;
        ax += bflo(u0) * wa + bflo(u1) * wb + bflo(u2) * wc + bflo(u3) * wd
            + bflo(u4) * we + bflo(u5) * wf + bflo(u6) * wg + bflo(u7) * wh;
        ay += bfhi(u0) * wa + bfhi(u1) * wb + bfhi(u2) * wc + bfhi(u3) * wd
            + bfhi(u4) * we + bfhi(u5) * wf + bfhi(u6) * wg + bfhi(u7) * wh;
    }
    for (; i < hi; ++i) {
        int s0 = csr2[i].x & 0xffff;
        uint u0 = ((const uint*)(h + (size_t)s0 * H))[t];
        float wa = dinv[s0] * dn;
        ax += bflo(u0) * wa;
        ay += bfhi(u0) * wa;
    }
    float2 bb = ((const float2*)bias)[t];
    ushort rx = f2bf(fmaxf(ax + bb.x, 0.f));
    ushort ry = f2bf(fmaxf(ay + bb.y, 0.f));
    p[(size_t)n * 64 + t] = (uint)rx | ((uint)ry << 16);
}

// MFMA bf16 GEMM: Y[NP][128] = X[NP][128] @ W  (Wt[c][k] transposed input).
__global__ __launch_bounds__(256) void k_gmm(const ushort* __restrict__ Xb,
                                             const ushort* __restrict__ Wt,
                                             ushort* __restrict__ Y) {
    __shared__ ushort Ws[16384];
    int t = threadIdx.x;
    for (int i = t; i < 2048; i += 256) {
        int o = i * 16;
        int phys = o ^ (((o >> 8) & 7) << 4);
        *(uint4*)((char*)Ws + phys) = *(const uint4*)((const char*)Wt + o);
    }
    __syncthreads();

    int lane = t & 63;
    int kg = lane >> 4;
    int lr = lane & 15;
    int row0 = blockIdx.x * 128 + (t >> 6) * 32;

    short8v a[2][4];
#pragma unroll
    for (int s = 0; s < 2; ++s)
#pragma unroll
        for (int kk = 0; kk < 4; ++kk)
            a[s][kk] = *(const short8v*)((const char*)Xb +
                ((size_t)(row0 + s * 16 + lr) * 128 + kk * 32 + kg * 8) * 2);

#pragma unroll
    for (int ct = 0; ct < 8; ++ct) {
        int c = ct * 16 + lr;
        f32x4 acc0 = {0.f, 0.f, 0.f, 0.f};
        f32x4 acc1 = {0.f, 0.f, 0.f, 0.f};
#pragma unroll
        for (int kk = 0; kk < 4; ++kk) {
            int o = c * 256 + kk * 64 + kg * 16;
            int phys = o ^ ((c & 7) << 4);
            short8v b = *(const short8v*)((const char*)Ws + phys);
            acc0 = __builtin_amdgcn_mfma_f32_16x16x32_bf16(a[0][kk], b, acc0, 0, 0, 0);
            acc1 = __builtin_amdgcn_mfma_f32_16x16x32_bf16(a[1][kk], b, acc1, 0, 0, 0);
        }
        int colo = ct * 16 + lr;
#pragma unroll
        for (int r = 0; r < 4; ++r) {
            Y[(size_t)(row0 + kg * 4 + r) * 128 + colo] = f2bf(acc0[r]);
            Y[(size_t)(row0 + 16 + kg * 4 + r) * 128 + colo] = f2bf(acc1[r]);
        }
    }
}

// Edge-parallel fused edge stage: 16-lane group per CSR entry, 8 entries/group,
// all 16 row-loads issued before compute.
#define EPB 128
__global__ __launch_bounds__(256) void k_edge(const int2* __restrict__ csr2,
                                              const ushort* __restrict__ u,
                                              const ushort* __restrict__ v,
                                              const float* __restrict__ bl1,
                                              const float* __restrict__ Wl2,
                                              const float* __restrict__ bl2,
                                              float* __restrict__ out) {
    int g = threadIdx.x >> 4;
    int l16 = threadIdx.x & 15;
    int base = blockIdx.x * EPB + g;

    float4 ba = *(const float4*)(bl1 + l16 * 8);
    float4 bb = *(const float4*)(bl1 + l16 * 8 + 4);
    float4 w0 = *(const float4*)(Wl2 + l16 * 16);
    float4 w1 = *(const float4*)(Wl2 + l16 * 16 + 4);
    float4 w2 = *(const float4*)(Wl2 + l16 * 16 + 8);
    float4 w3 = *(const float4*)(Wl2 + l16 * 16 + 12);
    float b20 = bl2[0], b21 = bl2[1];

    int2 e[8];
#pragma unroll
    for (int j = 0; j < 8; ++j) e[j] = csr2[base + j * 16];
    uint4 uu[8], vv[8];
#pragma unroll
    for (int j = 0; j < 8; ++j) {
        uu[j] = *(const uint4*)((const uint*)(u + (size_t)((uint)e[j].x & 0xffffu) * H) + l16 * 4);
        vv[j] = *(const uint4*)((const uint*)(v + (size_t)((uint)e[j].x >> 16) * H) + l16 * 4);
    }

#pragma unroll
    for (int q = 0; q < 8; ++q) {
        float h0 = fmaxf(bflo(uu[q].x) + bflo(vv[q].x) + ba.x, 0.f);
        float h1 = fmaxf(bfhi(uu[q].x) + bfhi(vv[q].x) + ba.y, 0.f);
        float h2 = fmaxf(bflo(uu[q].y) + bflo(vv[q].y) + ba.z, 0.f);
        float h3 = fmaxf(bfhi(uu[q].y) + bfhi(vv[q].y) + ba.w, 0.f);
        float h4 = fmaxf(bflo(uu[q].z) + bflo(vv[q].z) + bb.x, 0.f);
        float h5 = fmaxf(bfhi(uu[q].z) + bfhi(vv[q].z) + bb.y, 0.f);
        float h6 = fmaxf(bflo(uu[q].w) + bflo(vv[q].w) + bb.z, 0.f);
        float h7 = fmaxf(bfhi(uu[q].w) + bfhi(vv[q].w) + bb.w, 0.f);
        float p0 = h0 * w0.x + h1 * w0.z + h2 * w1.x + h3 * w1.z
                 + h4 * w2.x + h5 * w2.z + h6 * w3.x + h7 * w3.z;
        float p1 = h0 * w0.y + h1 * w0.w + h2 * w1.y + h3 * w1.w
                 + h4 * w2.y + h5 * w2.w + h6 * w3.y + h7 * w3.w;
#pragma unroll
        for (int m = 1; m < 16; m <<= 1) {
            p0 += __shfl_xor(p0, m, 64);
            p1 += __shfl_xor(p1, m, 64);
        }
        if (l16 == 0) {
            float2 o;
            o.x = fmaxf(p0 + b20, 0.f);
            o.y = fmaxf(p1 + b21, 0.f);
            *(float2*)(out + (size_t)e[q].y * 2) = o;
        }
    }
}

extern "C" void kernel_launch(void* const* d_in, const int* in_sizes, int n_in,
                              void* d_out, int out_size, void* d_ws, size_t ws_size,
                              hipStream_t stream) {
    const float* x   = (const float*)d_in[0];
    const float* W1  = (const float*)d_in[1];
    const float* b1  = (const float*)d_in[2];
    const float* W2  = (const float*)d_in[3];
    const float* b2  = (const float*)d_in[4];
    const float* Wl1 = (const float*)d_in[5];
    const float* bl1 = (const float*)d_in[6];
    const float* Wl2 = (const float*)d_in[7];
    const float* bl2 = (const float*)d_in[8];
    const int*   ei  = (const int*)d_in[9];
    const int* src = ei;
    const int* dst = ei + NE;
    float* out = (float*)d_out;

    char* ws = (char*)d_ws;
    size_t off = 0;
    auto alloc = [&](size_t bytes) -> void* {
        void* p = ws + off;
        off = (off + bytes + 255) & ~(size_t)255;
        return p;
    };
    float*  dinv     = (float*)alloc(NN * 4);
    int*    rowstart = (int*)alloc((NN + 1) * 4);
    int*    Bbase    = (int*)alloc((NB + 1) * 4);
    int*    Hg       = (int*)alloc((size_t)NBE * NB * 4);
    int*    Offb     = (int*)alloc((size_t)NBE * NB * 4);
    int2*   csr2     = (int2*)alloc((size_t)NE * 8);
    ushort* hbf      = (ushort*)alloc((size_t)NP * H * 2);   // h1 then h2
    ushort* pbf      = (ushort*)alloc((size_t)NP * H * 2);   // p1 then p2
    ushort* ubf      = (ushort*)alloc((size_t)NP * H * 2);
    ushort* vbf      = (ushort*)alloc((size_t)NP * H * 2);
    ushort* Wt2      = (ushort*)alloc(128 * 128 * 2);
    ushort* Wtu      = (ushort*)alloc(128 * 128 * 2);
    ushort* Wtv      = (ushort*)alloc(128 * 128 * 2);
    int2*   bin      = (int2*)ubf;  // alias; dead before gmm-u writes ubf

    k_hist<<<NBE, 512, 0, stream>>>(dst, Hg);
    k_bktscan<<<1, 512, 0, stream>>>(Hg, Bbase);
    k_hscan<<<1, 512, 0, stream>>>(Bbase, Hg, Offb);
    k_scatter<<<NBE, 512, 0, stream>>>(src, dst, Offb, bin);
    k_binB<<<NB, 256, 0, stream>>>(Bbase, bin, csr2, rowstart, dinv);
    k_wcvt<<<192, 256, 0, stream>>>(W2, Wl1, Wt2, Wtu, Wtv);

    k_xw1<<<NN / 2, 256, 0, stream>>>(x, W1, hbf);                                // h1
    k_agg<<<NN / 4, 256, 0, stream>>>(hbf, dinv, rowstart, csr2, b1, (uint*)pbf); // p1
    k_gmm<<<NP / 128, 256, 0, stream>>>(pbf, Wt2, hbf);                           // h2
    k_agg<<<NN / 4, 256, 0, stream>>>(hbf, dinv, rowstart, csr2, b2, (uint*)pbf); // p2
    k_gmm<<<NP / 128, 256, 0, stream>>>(pbf, Wtu, ubf);                           // u
    k_gmm<<<NP / 128, 256, 0, stream>>>(pbf, Wtv, vbf);                           // v
    k_edge<<<NE / EPB, 256, 0, stream>>>(csr2, ubf, vbf, bl1, Wl2, bl2, out);
}

// Round 11
// 204.365 us; speedup vs baseline: 1.9810x; 1.0071x over previous
//
#include <hip/hip_runtime.h>

#define NN 50000
#define NE 800000
#define F_IN 8
#define H 128
#define BSH 7
#define NB ((NN + 127) >> BSH)         // 391 buckets, 128 dsts each
#define EBLK 4096
#define NBE ((NE + EBLK - 1) / EBLK)   // 196 edge blocks
#define NP 50048                       // padded rows; 50048 = 391*128 exactly
#define ECH 64                         // csr entries per edge-chunk
#define NCHUNK (NE / ECH)              // 12500
#define EGRID 1250
#define KPB (NCHUNK / EGRID)           // 10 chunks/block, contiguous

typedef unsigned int uint;
typedef unsigned short ushort;
typedef __attribute__((ext_vector_type(8))) short short8v;
typedef __attribute__((ext_vector_type(4))) float f32x4;

__device__ __forceinline__ ushort f2bf(float f) {
    uint u = __float_as_uint(f);
    uint r = (u + 0x7fffu + ((u >> 16) & 1u)) >> 16;
    return (ushort)r;
}
__device__ __forceinline__ float bflo(uint u) { return __uint_as_float(u << 16); }
__device__ __forceinline__ float bfhi(uint u) { return __uint_as_float(u & 0xffff0000u); }

// ---- bucket histogram over edge blocks ----
__global__ __launch_bounds__(512) void k_hist(const int* __restrict__ dst,
                                              int* __restrict__ Hg) {
    __shared__ int h[NB];
    int t = threadIdx.x, blk = blockIdx.x;
    for (int b = t; b < NB; b += 512) h[b] = 0;
    __syncthreads();
    int e0 = blk * EBLK;
    int e1 = e0 + EBLK; if (e1 > NE) e1 = NE;
    for (int i = e0 + t; i < e1; i += 512) atomicAdd(&h[dst[i] >> BSH], 1);
    __syncthreads();
    for (int b = t; b < NB; b += 512) Hg[blk * NB + b] = h[b];
}

// ---- merged: bucket bases (col-sum + scan) AND per-(edge-block,bucket) offsets ----
__global__ __launch_bounds__(512) void k_scans(const int* __restrict__ Hg,
                                               int* __restrict__ Bbase,
                                               int* __restrict__ Off) {
    __shared__ int s[512];
    int t = threadIdx.x;
    int acc = 0;
    if (t < NB)
        for (int e = 0; e < NBE; ++e) acc += Hg[e * NB + t];
    s[t] = acc;
    __syncthreads();
    for (int off = 1; off < 512; off <<= 1) {
        int v = (t >= off) ? s[t - off] : 0;
        __syncthreads();
        s[t] += v;
        __syncthreads();
    }
    int base = (t == 0) ? 0 : s[t - 1];
    if (t <= NB) Bbase[t] = base;
    if (t < NB) {
        int run = base;
        for (int e = 0; e < NBE; ++e) {
            Off[e * NB + t] = run;
            run += Hg[e * NB + t];
        }
    }
}

// ---- deterministic scatter into bucket-contiguous regions ----
__global__ __launch_bounds__(512) void k_scatter(const int* __restrict__ src,
                                                 const int* __restrict__ dst,
                                                 const int* __restrict__ Off,
                                                 int2* __restrict__ bin) {
    __shared__ int cur[NB];
    int t = threadIdx.x, blk = blockIdx.x;
    for (int b = t; b < NB; b += 512) cur[b] = Off[blk * NB + b];
    __syncthreads();
    int e0 = blk * EBLK;
    int e1 = e0 + EBLK; if (e1 > NE) e1 = NE;
    for (int i = e0 + t; i < e1; i += 512) {
        int d = dst[i];
        int b = d >> BSH;
        int pos = atomicAdd(&cur[b], 1);
        bin[pos] = make_int2((src[i] & 0xffff) | ((d & ((1 << BSH) - 1)) << 16), i);
    }
}

// ---- bucket -> per-dst CSR; derives rowstart + dinv ----
__global__ __launch_bounds__(256) void k_binB(const int* __restrict__ Bbase,
                                              const int2* __restrict__ bin,
                                              int2* __restrict__ csr2,
                                              int* __restrict__ rowstart,
                                              float* __restrict__ dinv) {
    int b = blockIdx.x, t = threadIdx.x;
    __shared__ int cnt[128];
    __shared__ int cur[128];
    int base = Bbase[b];
    int end = Bbase[b + 1];
    if (t < 128) cnt[t] = 0;
    __syncthreads();
    for (int idx = base + t; idx < end; idx += 256)
        atomicAdd(&cnt[(uint)bin[idx].x >> 16], 1);
    __syncthreads();
    int myc = (t < 128) ? cnt[t] : 0;
    for (int off = 1; off < 128; off <<= 1) {
        int v = (t >= off && t < 128) ? cnt[t - off] : 0;
        __syncthreads();
        if (t < 128) cnt[t] += v;
        __syncthreads();
    }
    if (t < 128) {
        int startpos = base + cnt[t] - myc;
        int n = (b << BSH) + t;
        if (n < NN) {
            rowstart[n] = startpos;
            dinv[n] = rsqrtf((float)(myc + 1));
        }
        if (b == NB - 1 && t == 127) rowstart[NN] = NE;
        cur[t] = startpos;
    }
    __syncthreads();
    for (int idx = base + t; idx < end; idx += 256) {
        int2 e = bin[idx];
        int ld = (int)((uint)e.x >> 16);
        uint d = (uint)((b << BSH) + ld);
        int pos = atomicAdd(&cur[ld], 1);
        csr2[pos] = make_int2((int)(((uint)e.x & 0xffffu) | (d << 16)), e.y);
    }
}

// Convert W2 / Wl1(top,bot) to bf16 transposed: Wt[c*128 + k] = W[k][c]
__global__ __launch_bounds__(256) void k_wcvt(const float* __restrict__ W2,
                                              const float* __restrict__ Wl1,
                                              ushort* __restrict__ Wt2,
                                              ushort* __restrict__ Wtu,
                                              ushort* __restrict__ Wtv) {
    int id = blockIdx.x * 256 + threadIdx.x;
    int m = id >> 14;
    int r = id & 16383;
    int c = r >> 7, k = r & 127;
    float v;
    ushort* dstp;
    if (m == 0)      { v = W2[k * 128 + c];          dstp = Wt2; }
    else if (m == 1) { v = Wl1[k * 128 + c];         dstp = Wtu; }
    else             { v = Wl1[(128 + k) * 128 + c]; dstp = Wtv; }
    dstp[r] = f2bf(v);
}

// h[n][j] = sum_k x[n][k] * W1[k][j], bf16 output
__global__ __launch_bounds__(256) void k_xw1(const float* __restrict__ x,
                                             const float* __restrict__ W1,
                                             ushort* __restrict__ h) {
    int t = threadIdx.x;
    int n = blockIdx.x * 2 + (t >> 7);
    int j = t & 127;
    const float* xr = x + n * F_IN;
    float acc = 0.f;
#pragma unroll
    for (int k = 0; k < F_IN; ++k) acc += xr[k] * W1[k * H + j];
    h[n * H + j] = f2bf(acc);
}

// p[n] = relu( h[n]*dinv[n]^2 + sum_s h[s]*dinv[s]*dinv[n] + bias ), bf16 out
__global__ __launch_bounds__(256) void k_agg(const ushort* __restrict__ h,
                                             const float* __restrict__ dinv,
                                             const int* __restrict__ rowstart,
                                             const int2* __restrict__ csr2,
                                             const float* __restrict__ bias,
                                             uint* __restrict__ p) {
    int n = blockIdx.x * 4 + (threadIdx.x >> 6);
    int t = threadIdx.x & 63;
    float dn = dinv[n];
    uint us = ((const uint*)(h + (size_t)n * H))[t];
    float w0 = dn * dn;
    float ax = bflo(us) * w0;
    float ay = bfhi(us) * w0;
    int lo = rowstart[n], hi = rowstart[n + 1];
    int i = lo;
    for (; i + 7 < hi; i += 8) {
        int s0 = csr2[i + 0].x & 0xffff;
        int s1 = csr2[i + 1].x & 0xffff;
        int s2 = csr2[i + 2].x & 0xffff;
        int s3 = csr2[i + 3].x & 0xffff;
        int s4 = csr2[i + 4].x & 0xffff;
        int s5 = csr2[i + 5].x & 0xffff;
        int s6 = csr2[i + 6].x & 0xffff;
        int s7 = csr2[i + 7].x & 0xffff;
        uint u0 = ((const uint*)(h + (size_t)s0 * H))[t];
        uint u1 = ((const uint*)(h + (size_t)s1 * H))[t];
        uint u2 = ((const uint*)(h + (size_t)s2 * H))[t];
        uint u3 = ((const uint*)(h + (size_t)s3 * H))[t];
        uint u4 = ((const uint*)(h + (size_t)s4 * H))[t];
        uint u5 = ((const uint*)(h + (size_t)s5 * H))[t];
        uint u6 = ((const uint*)(h + (size_t)s6 * H))[t];
        uint u7 = ((const uint*)(h + (size_t)s7 * H))[t];
        float wa = dinv[s0] * dn, wb = dinv[s1] * dn, wc = dinv[s2] * dn, wd = dinv[s3] * dn;
        float we = dinv[s4] * dn, wf = dinv[s5] * dn, wg = dinv[s6] * dn, wh = dinv[s7] * dn;
        ax += bflo(u0) * wa + bflo(u1) * wb + bflo(u2) * wc + bflo(u3) * wd
            + bflo(u4) * we + bflo(u5) * wf + bflo(u6) * wg + bflo(u7) * wh;
        ay += bfhi(u0) * wa + bfhi(u1) * wb + bfhi(u2) * wc + bfhi(u3) * wd
            + bfhi(u4) * we + bfhi(u5) * wf + bfhi(u6) * wg + bfhi(u7) * wh;
    }
    for (; i < hi; ++i) {
        int s0 = csr2[i].x & 0xffff;
        uint u0 = ((const uint*)(h + (size_t)s0 * H))[t];
        float wa = dinv[s0] * dn;
        ax += bflo(u0) * wa;
        ay += bfhi(u0) * wa;
    }
    float2 bb = ((const float2*)bias)[t];
    ushort rx = f2bf(fmaxf(ax + bb.x, 0.f));
    ushort ry = f2bf(fmaxf(ay + bb.y, 0.f));
    p[(size_t)n * 64 + t] = (uint)rx | ((uint)ry << 16);
}

// MFMA bf16 GEMM: Y = X @ W (Wt[c][k] transposed input)
__global__ __launch_bounds__(256) void k_gmm(const ushort* __restrict__ Xb,
                                             const ushort* __restrict__ Wt,
                                             ushort* __restrict__ Y) {
    __shared__ ushort Ws[16384];
    int t = threadIdx.x;
    for (int i = t; i < 2048; i += 256) {
        int o = i * 16;
        int phys = o ^ (((o >> 8) & 7) << 4);
        *(uint4*)((char*)Ws + phys) = *(const uint4*)((const char*)Wt + o);
    }
    __syncthreads();
    int lane = t & 63;
    int kg = lane >> 4;
    int lr = lane & 15;
    int row0 = blockIdx.x * 128 + (t >> 6) * 32;
    short8v a[2][4];
#pragma unroll
    for (int s = 0; s < 2; ++s)
#pragma unroll
        for (int kk = 0; kk < 4; ++kk)
            a[s][kk] = *(const short8v*)((const char*)Xb +
                ((size_t)(row0 + s * 16 + lr) * 128 + kk * 32 + kg * 8) * 2);
#pragma unroll
    for (int ct = 0; ct < 8; ++ct) {
        int c = ct * 16 + lr;
        f32x4 acc0 = {0.f, 0.f, 0.f, 0.f};
        f32x4 acc1 = {0.f, 0.f, 0.f, 0.f};
#pragma unroll
        for (int kk = 0; kk < 4; ++kk) {
            int o = c * 256 + kk * 64 + kg * 16;
            int phys = o ^ ((c & 7) << 4);
            short8v b = *(const short8v*)((const char*)Ws + phys);
            acc0 = __builtin_amdgcn_mfma_f32_16x16x32_bf16(a[0][kk], b, acc0, 0, 0, 0);
            acc1 = __builtin_amdgcn_mfma_f32_16x16x32_bf16(a[1][kk], b, acc1, 0, 0, 0);
        }
        int colo = ct * 16 + lr;
#pragma unroll
        for (int r = 0; r < 4; ++r) {
            Y[(size_t)(row0 + kg * 4 + r) * 128 + colo] = f2bf(acc0[r]);
            Y[(size_t)(row0 + 16 + kg * 4 + r) * 128 + colo] = f2bf(acc1[r]);
        }
    }
}

// Fused double GEMM: Yu = X @ Wu, Yv = X @ Wv; X read once, both W in LDS.
__global__ __launch_bounds__(256) void k_gmm2(const ushort* __restrict__ Xb,
                                              const ushort* __restrict__ Wtu,
                                              const ushort* __restrict__ Wtv,
                                              ushort* __restrict__ Yu,
                                              ushort* __restrict__ Yv) {
    __shared__ ushort Ws[2][16384];
    int t = threadIdx.x;
    for (int i = t; i < 2048; i += 256) {
        int o = i * 16;
        int phys = o ^ (((o >> 8) & 7) << 4);
        *(uint4*)((char*)Ws[0] + phys) = *(const uint4*)((const char*)Wtu + o);
        *(uint4*)((char*)Ws[1] + phys) = *(const uint4*)((const char*)Wtv + o);
    }
    __syncthreads();
    int lane = t & 63;
    int kg = lane >> 4;
    int lr = lane & 15;
    int row0 = blockIdx.x * 128 + (t >> 6) * 32;
    short8v a[2][4];
#pragma unroll
    for (int s = 0; s < 2; ++s)
#pragma unroll
        for (int kk = 0; kk < 4; ++kk)
            a[s][kk] = *(const short8v*)((const char*)Xb +
                ((size_t)(row0 + s * 16 + lr) * 128 + kk * 32 + kg * 8) * 2);
#pragma unroll
    for (int ct = 0; ct < 8; ++ct) {
        int c = ct * 16 + lr;
        f32x4 au0 = {0.f, 0.f, 0.f, 0.f};
        f32x4 au1 = {0.f, 0.f, 0.f, 0.f};
        f32x4 av0 = {0.f, 0.f, 0.f, 0.f};
        f32x4 av1 = {0.f, 0.f, 0.f, 0.f};
#pragma unroll
        for (int kk = 0; kk < 4; ++kk) {
            int o = c * 256 + kk * 64 + kg * 16;
            int phys = o ^ ((c & 7) << 4);
            short8v bu = *(const short8v*)((const char*)Ws[0] + phys);
            short8v bv = *(const short8v*)((const char*)Ws[1] + phys);
            au0 = __builtin_amdgcn_mfma_f32_16x16x32_bf16(a[0][kk], bu, au0, 0, 0, 0);
            au1 = __builtin_amdgcn_mfma_f32_16x16x32_bf16(a[1][kk], bu, au1, 0, 0, 0);
            av0 = __builtin_amdgcn_mfma_f32_16x16x32_bf16(a[0][kk], bv, av0, 0, 0, 0);
            av1 = __builtin_amdgcn_mfma_f32_16x16x32_bf16(a[1][kk], bv, av1, 0, 0, 0);
        }
        int colo = ct * 16 + lr;
#pragma unroll
        for (int r = 0; r < 4; ++r) {
            Yu[(size_t)(row0 + kg * 4 + r) * 128 + colo] = f2bf(au0[r]);
            Yu[(size_t)(row0 + 16 + kg * 4 + r) * 128 + colo] = f2bf(au1[r]);
            Yv[(size_t)(row0 + kg * 4 + r) * 128 + colo] = f2bf(av0[r]);
            Yv[(size_t)(row0 + 16 + kg * 4 + r) * 128 + colo] = f2bf(av1[r]);
        }
    }
}

// ---- persistent, software-pipelined edge stage ----
__device__ __forceinline__ void edge_load4(const int2* __restrict__ csr2,
                                           const ushort* __restrict__ u,
                                           const ushort* __restrict__ v,
                                           int ch, int g, int l16,
                                           int2 (&e)[4], uint4 (&uu)[4], uint4 (&vv)[4]) {
    int bb = ch * ECH + g;
#pragma unroll
    for (int j = 0; j < 4; ++j) e[j] = csr2[bb + j * 16];
#pragma unroll
    for (int j = 0; j < 4; ++j) {
        uu[j] = *(const uint4*)((const uint*)(u + (size_t)((uint)e[j].x & 0xffffu) * H) + l16 * 4);
        vv[j] = *(const uint4*)((const uint*)(v + (size_t)((uint)e[j].x >> 16) * H) + l16 * 4);
    }
}

__device__ __forceinline__ void edge_comp4(const int2 (&e)[4], const uint4 (&uu)[4], const uint4 (&vv)[4],
                                           float4 ba, float4 bb, float4 w0, float4 w1,
                                           float4 w2, float4 w3, float b20, float b21,
                                           int l16, float* __restrict__ out) {
#pragma unroll
    for (int q = 0; q < 4; ++q) {
        float h0 = fmaxf(bflo(uu[q].x) + bflo(vv[q].x) + ba.x, 0.f);
        float h1 = fmaxf(bfhi(uu[q].x) + bfhi(vv[q].x) + ba.y, 0.f);
        float h2 = fmaxf(bflo(uu[q].y) + bflo(vv[q].y) + ba.z, 0.f);
        float h3 = fmaxf(bfhi(uu[q].y) + bfhi(vv[q].y) + ba.w, 0.f);
        float h4 = fmaxf(bflo(uu[q].z) + bflo(vv[q].z) + bb.x, 0.f);
        float h5 = fmaxf(bfhi(uu[q].z) + bfhi(vv[q].z) + bb.y, 0.f);
        float h6 = fmaxf(bflo(uu[q].w) + bflo(vv[q].w) + bb.z, 0.f);
        float h7 = fmaxf(bfhi(uu[q].w) + bfhi(vv[q].w) + bb.w, 0.f);
        float p0 = h0 * w0.x + h1 * w0.z + h2 * w1.x + h3 * w1.z
                 + h4 * w2.x + h5 * w2.z + h6 * w3.x + h7 * w3.z;
        float p1 = h0 * w0.y + h1 * w0.w + h2 * w1.y + h3 * w1.w
                 + h4 * w2.y + h5 * w2.w + h6 * w3.y + h7 * w3.w;
#pragma unroll
        for (int m = 1; m < 16; m <<= 1) {
            p0 += __shfl_xor(p0, m, 64);
            p1 += __shfl_xor(p1, m, 64);
        }
        if (l16 == 0) {
            float2 o;
            o.x = fmaxf(p0 + b20, 0.f);
            o.y = fmaxf(p1 + b21, 0.f);
            *(float2*)(out + (size_t)e[q].y * 2) = o;
        }
    }
}

__global__ __launch_bounds__(256) void k_edge(const int2* __restrict__ csr2,
                                              const ushort* __restrict__ u,
                                              const ushort* __restrict__ v,
                                              const float* __restrict__ bl1,
                                              const float* __restrict__ Wl2,
                                              const float* __restrict__ bl2,
                                              float* __restrict__ out) {
    int g = threadIdx.x >> 4;
    int l16 = threadIdx.x & 15;
    int c0 = blockIdx.x * KPB;

    float4 ba = *(const float4*)(bl1 + l16 * 8);
    float4 bb = *(const float4*)(bl1 + l16 * 8 + 4);
    float4 w0 = *(const float4*)(Wl2 + l16 * 16);
    float4 w1 = *(const float4*)(Wl2 + l16 * 16 + 4);
    float4 w2 = *(const float4*)(Wl2 + l16 * 16 + 8);
    float4 w3 = *(const float4*)(Wl2 + l16 * 16 + 12);
    float b20 = bl2[0], b21 = bl2[1];

    int2 eA[4], eB[4];
    uint4 uA[4], vA[4], uB[4], vB[4];

    edge_load4(csr2, u, v, c0, g, l16, eA, uA, vA);
#pragma unroll 1
    for (int it = 0; it < (KPB - 2) / 2; ++it) {           // it = 0..3, chunks c0..c0+7
        edge_load4(csr2, u, v, c0 + 2 * it + 1, g, l16, eB, uB, vB);
        edge_comp4(eA, uA, vA, ba, bb, w0, w1, w2, w3, b20, b21, l16, out);
        edge_load4(csr2, u, v, c0 + 2 * it + 2, g, l16, eA, uA, vA);
        edge_comp4(eB, uB, vB, ba, bb, w0, w1, w2, w3, b20, b21, l16, out);
    }
    edge_load4(csr2, u, v, c0 + KPB - 1, g, l16, eB, uB, vB);
    edge_comp4(eA, uA, vA, ba, bb, w0, w1, w2, w3, b20, b21, l16, out);   // chunk c0+8
    edge_comp4(eB, uB, vB, ba, bb, w0, w1, w2, w3, b20, b21, l16, out);   // chunk c0+9
}

extern "C" void kernel_launch(void* const* d_in, const int* in_sizes, int n_in,
                              void* d_out, int out_size, void* d_ws, size_t ws_size,
                              hipStream_t stream) {
    const float* x   = (const float*)d_in[0];
    const float* W1  = (const float*)d_in[1];
    const float* b1  = (const float*)d_in[2];
    const float* W2  = (const float*)d_in[3];
    const float* b2  = (const float*)d_in[4];
    const float* Wl1 = (const float*)d_in[5];
    const float* bl1 = (const float*)d_in[6];
    const float* Wl2 = (const float*)d_in[7];
    const float* bl2 = (const float*)d_in[8];
    const int*   ei  = (const int*)d_in[9];
    const int* src = ei;
    const int* dst = ei + NE;
    float* out = (float*)d_out;

    char* ws = (char*)d_ws;
    size_t off = 0;
    auto alloc = [&](size_t bytes) -> void* {
        void* p = ws + off;
        off = (off + bytes + 255) & ~(size_t)255;
        return p;
    };
    float*  dinv     = (float*)alloc(NN * 4);
    int*    rowstart = (int*)alloc((NN + 1) * 4);
    int*    Bbase    = (int*)alloc((NB + 1) * 4);
    int*    Hg       = (int*)alloc((size_t)NBE * NB * 4);
    int*    Offb     = (int*)alloc((size_t)NBE * NB * 4);
    int2*   csr2     = (int2*)alloc((size_t)NE * 8);
    ushort* hbf      = (ushort*)alloc((size_t)NP * H * 2);   // h1 then h2
    ushort* pbf      = (ushort*)alloc((size_t)NP * H * 2);   // p1 then p2
    ushort* ubf      = (ushort*)alloc((size_t)NP * H * 2);
    ushort* vbf      = (ushort*)alloc((size_t)NP * H * 2);
    ushort* Wt2      = (ushort*)alloc(128 * 128 * 2);
    ushort* Wtu      = (ushort*)alloc(128 * 128 * 2);
    ushort* Wtv      = (ushort*)alloc(128 * 128 * 2);
    int2*   bin      = (int2*)ubf;  // alias; dead before k_gmm2 writes ubf

    k_hist<<<NBE, 512, 0, stream>>>(dst, Hg);
    k_scans<<<1, 512, 0, stream>>>(Hg, Bbase, Offb);
    k_scatter<<<NBE, 512, 0, stream>>>(src, dst, Offb, bin);
    k_binB<<<NB, 256, 0, stream>>>(Bbase, bin, csr2, rowstart, dinv);
    k_wcvt<<<192, 256, 0, stream>>>(W2, Wl1, Wt2, Wtu, Wtv);

    k_xw1<<<NN / 2, 256, 0, stream>>>(x, W1, hbf);                                // h1
    k_agg<<<NN / 4, 256, 0, stream>>>(hbf, dinv, rowstart, csr2, b1, (uint*)pbf); // p1
    k_gmm<<<NP / 128, 256, 0, stream>>>(pbf, Wt2, hbf);                           // h2
    k_agg<<<NN / 4, 256, 0, stream>>>(hbf, dinv, rowstart, csr2, b2, (uint*)pbf); // p2
    k_gmm2<<<NP / 128, 256, 0, stream>>>(pbf, Wtu, Wtv, ubf, vbf);                // u, v
    k_edge<<<EGRID, 256, 0, stream>>>(csr2, ubf, vbf, bl1, Wl2, bl2, out);
}

// Round 12
// 200.091 us; speedup vs baseline: 2.0233x; 1.0214x over previous
//
#include <hip/hip_runtime.h>

#define NN 50000
#define NE 800000
#define F_IN 8
#define H 128
#define BSH 7
#define NB ((NN + 127) >> BSH)         // 391 buckets, 128 dsts each
#define EBLK 4096
#define NBE ((NE + EBLK - 1) / EBLK)   // 196 edge blocks
#define NP 50048                       // padded rows; 50048 = 391*128 exactly

typedef unsigned int uint;
typedef unsigned short ushort;
typedef __attribute__((ext_vector_type(8))) short short8v;
typedef __attribute__((ext_vector_type(4))) float f32x4;

__device__ __forceinline__ ushort f2bf(float f) {
    uint u = __float_as_uint(f);
    uint r = (u + 0x7fffu + ((u >> 16) & 1u)) >> 16;
    return (ushort)r;
}
__device__ __forceinline__ float bflo(uint u) { return __uint_as_float(u << 16); }
__device__ __forceinline__ float bfhi(uint u) { return __uint_as_float(u & 0xffff0000u); }

// ---- bucket histogram over edge blocks ----
__global__ __launch_bounds__(512) void k_hist(const int* __restrict__ dst,
                                              int* __restrict__ Hg) {
    __shared__ int h[NB];
    int t = threadIdx.x, blk = blockIdx.x;
    for (int b = t; b < NB; b += 512) h[b] = 0;
    __syncthreads();
    int e0 = blk * EBLK;
    int e1 = e0 + EBLK; if (e1 > NE) e1 = NE;
    for (int i = e0 + t; i < e1; i += 512) atomicAdd(&h[dst[i] >> BSH], 1);
    __syncthreads();
    for (int b = t; b < NB; b += 512) Hg[blk * NB + b] = h[b];
}

// ---- merged: bucket bases (col-sum + scan) AND per-(edge-block,bucket) offsets ----
__global__ __launch_bounds__(512) void k_scans(const int* __restrict__ Hg,
                                               int* __restrict__ Bbase,
                                               int* __restrict__ Off) {
    __shared__ int s[512];
    int t = threadIdx.x;
    int acc = 0;
    if (t < NB)
        for (int e = 0; e < NBE; ++e) acc += Hg[e * NB + t];
    s[t] = acc;
    __syncthreads();
    for (int off = 1; off < 512; off <<= 1) {
        int v = (t >= off) ? s[t - off] : 0;
        __syncthreads();
        s[t] += v;
        __syncthreads();
    }
    int base = (t == 0) ? 0 : s[t - 1];
    if (t <= NB) Bbase[t] = base;
    if (t < NB) {
        int run = base;
        for (int e = 0; e < NBE; ++e) {
            Off[e * NB + t] = run;
            run += Hg[e * NB + t];
        }
    }
}

// ---- deterministic scatter into bucket-contiguous regions ----
__global__ __launch_bounds__(512) void k_scatter(const int* __restrict__ src,
                                                 const int* __restrict__ dst,
                                                 const int* __restrict__ Off,
                                                 int2* __restrict__ bin) {
    __shared__ int cur[NB];
    int t = threadIdx.x, blk = blockIdx.x;
    for (int b = t; b < NB; b += 512) cur[b] = Off[blk * NB + b];
    __syncthreads();
    int e0 = blk * EBLK;
    int e1 = e0 + EBLK; if (e1 > NE) e1 = NE;
    for (int i = e0 + t; i < e1; i += 512) {
        int d = dst[i];
        int b = d >> BSH;
        int pos = atomicAdd(&cur[b], 1);
        bin[pos] = make_int2((src[i] & 0xffff) | ((d & ((1 << BSH) - 1)) << 16), i);
    }
}

// ---- bucket -> per-dst CSR; derives rowstart + dinv ----
__global__ __launch_bounds__(256) void k_binB(const int* __restrict__ Bbase,
                                              const int2* __restrict__ bin,
                                              int2* __restrict__ csr2,
                                              int* __restrict__ rowstart,
                                              float* __restrict__ dinv) {
    int b = blockIdx.x, t = threadIdx.x;
    __shared__ int cnt[128];
    __shared__ int cur[128];
    int base = Bbase[b];
    int end = Bbase[b + 1];
    if (t < 128) cnt[t] = 0;
    __syncthreads();
    for (int idx = base + t; idx < end; idx += 256)
        atomicAdd(&cnt[(uint)bin[idx].x >> 16], 1);
    __syncthreads();
    int myc = (t < 128) ? cnt[t] : 0;
    for (int off = 1; off < 128; off <<= 1) {
        int v = (t >= off && t < 128) ? cnt[t - off] : 0;
        __syncthreads();
        if (t < 128) cnt[t] += v;
        __syncthreads();
    }
    if (t < 128) {
        int startpos = base + cnt[t] - myc;
        int n = (b << BSH) + t;
        if (n < NN) {
            rowstart[n] = startpos;
            dinv[n] = rsqrtf((float)(myc + 1));
        }
        if (b == NB - 1 && t == 127) rowstart[NN] = NE;
        cur[t] = startpos;
    }
    __syncthreads();
    for (int idx = base + t; idx < end; idx += 256) {
        int2 e = bin[idx];
        int ld = (int)((uint)e.x >> 16);
        uint d = (uint)((b << BSH) + ld);
        int pos = atomicAdd(&cur[ld], 1);
        csr2[pos] = make_int2((int)(((uint)e.x & 0xffffu) | (d << 16)), e.y);
    }
}

// Convert W2 / Wl1(top,bot) to bf16 transposed: Wt[c*128 + k] = W[k][c]
__global__ __launch_bounds__(256) void k_wcvt(const float* __restrict__ W2,
                                              const float* __restrict__ Wl1,
                                              ushort* __restrict__ Wt2,
                                              ushort* __restrict__ Wtu,
                                              ushort* __restrict__ Wtv) {
    int id = blockIdx.x * 256 + threadIdx.x;
    int m = id >> 14;
    int r = id & 16383;
    int c = r >> 7, k = r & 127;
    float v;
    ushort* dstp;
    if (m == 0)      { v = W2[k * 128 + c];          dstp = Wt2; }
    else if (m == 1) { v = Wl1[k * 128 + c];         dstp = Wtu; }
    else             { v = Wl1[(128 + k) * 128 + c]; dstp = Wtv; }
    dstp[r] = f2bf(v);
}

// h[n][j] = sum_k x[n][k] * W1[k][j], bf16 output
__global__ __launch_bounds__(256) void k_xw1(const float* __restrict__ x,
                                             const float* __restrict__ W1,
                                             ushort* __restrict__ h) {
    int t = threadIdx.x;
    int n = blockIdx.x * 2 + (t >> 7);
    int j = t & 127;
    const float* xr = x + n * F_IN;
    float acc = 0.f;
#pragma unroll
    for (int k = 0; k < F_IN; ++k) acc += xr[k] * W1[k * H + j];
    h[n * H + j] = f2bf(acc);
}

// p[n] = relu( h[n]*dinv[n]^2 + sum_s h[s]*dinv[s]*dinv[n] + bias ), bf16 out
__global__ __launch_bounds__(256) void k_agg(const ushort* __restrict__ h,
                                             const float* __restrict__ dinv,
                                             const int* __restrict__ rowstart,
                                             const int2* __restrict__ csr2,
                                             const float* __restrict__ bias,
                                             uint* __restrict__ p) {
    int n = blockIdx.x * 4 + (threadIdx.x >> 6);
    int t = threadIdx.x & 63;
    float dn = dinv[n];
    uint us = ((const uint*)(h + (size_t)n * H))[t];
    float w0 = dn * dn;
    float ax = bflo(us) * w0;
    float ay = bfhi(us) * w0;
    int lo = rowstart[n], hi = rowstart[n + 1];
    int i = lo;
    for (; i + 7 < hi; i += 8) {
        int s0 = csr2[i + 0].x & 0xffff;
        int s1 = csr2[i + 1].x & 0xffff;
        int s2 = csr2[i + 2].x & 0xffff;
        int s3 = csr2[i + 3].x & 0xffff;
        int s4 = csr2[i + 4].x & 0xffff;
        int s5 = csr2[i + 5].x & 0xffff;
        int s6 = csr2[i + 6].x & 0xffff;
        int s7 = csr2[i + 7].x & 0xffff;
        uint u0 = ((const uint*)(h + (size_t)s0 * H))[t];
        uint u1 = ((const uint*)(h + (size_t)s1 * H))[t];
        uint u2 = ((const uint*)(h + (size_t)s2 * H))[t];
        uint u3 = ((const uint*)(h + (size_t)s3 * H))[t];
        uint u4 = ((const uint*)(h + (size_t)s4 * H))[t];
        uint u5 = ((const uint*)(h + (size_t)s5 * H))[t];
        uint u6 = ((const uint*)(h + (size_t)s6 * H))[t];
        uint u7 = ((const uint*)(h + (size_t)s7 * H))[t];
        float wa = dinv[s0] * dn, wb = dinv[s1] * dn, wc = dinv[s2] * dn, wd = dinv[s3] * dn;
        float we = dinv[s4] * dn, wf = dinv[s5] * dn, wg = dinv[s6] * dn, wh = dinv[s7] * dn;
        ax += bflo(u0) * wa + bflo(u1) * wb + bflo(u2) * wc + bflo(u3) * wd
            + bflo(u4) * we + bflo(u5) * wf + bflo(u6) * wg + bflo(u7) * wh;
        ay += bfhi(u0) * wa + bfhi(u1) * wb + bfhi(u2) * wc + bfhi(u3) * wd
            + bfhi(u4) * we + bfhi(u5) * wf + bfhi(u6) * wg + bfhi(u7) * wh;
    }
    for (; i < hi; ++i) {
        int s0 = csr2[i].x & 0xffff;
        uint u0 = ((const uint*)(h + (size_t)s0 * H))[t];
        float wa = dinv[s0] * dn;
        ax += bflo(u0) * wa;
        ay += bfhi(u0) * wa;
    }
    float2 bb = ((const float2*)bias)[t];
    ushort rx = f2bf(fmaxf(ax + bb.x, 0.f));
    ushort ry = f2bf(fmaxf(ay + bb.y, 0.f));
    p[(size_t)n * 64 + t] = (uint)rx | ((uint)ry << 16);
}

// MFMA bf16 GEMM: Y = X @ W (Wt[c][k] transposed input)
__global__ __launch_bounds__(256) void k_gmm(const ushort* __restrict__ Xb,
                                             const ushort* __restrict__ Wt,
                                             ushort* __restrict__ Y) {
    __shared__ ushort Ws[16384];
    int t = threadIdx.x;
    for (int i = t; i < 2048; i += 256) {
        int o = i * 16;
        int phys = o ^ (((o >> 8) & 7) << 4);
        *(uint4*)((char*)Ws + phys) = *(const uint4*)((const char*)Wt + o);
    }
    __syncthreads();
    int lane = t & 63;
    int kg = lane >> 4;
    int lr = lane & 15;
    int row0 = blockIdx.x * 128 + (t >> 6) * 32;
    short8v a[2][4];
#pragma unroll
    for (int s = 0; s < 2; ++s)
#pragma unroll
        for (int kk = 0; kk < 4; ++kk)
            a[s][kk] = *(const short8v*)((const char*)Xb +
                ((size_t)(row0 + s * 16 + lr) * 128 + kk * 32 + kg * 8) * 2);
#pragma unroll
    for (int ct = 0; ct < 8; ++ct) {
        int c = ct * 16 + lr;
        f32x4 acc0 = {0.f, 0.f, 0.f, 0.f};
        f32x4 acc1 = {0.f, 0.f, 0.f, 0.f};
#pragma unroll
        for (int kk = 0; kk < 4; ++kk) {
            int o = c * 256 + kk * 64 + kg * 16;
            int phys = o ^ ((c & 7) << 4);
            short8v b = *(const short8v*)((const char*)Ws + phys);
            acc0 = __builtin_amdgcn_mfma_f32_16x16x32_bf16(a[0][kk], b, acc0, 0, 0, 0);
            acc1 = __builtin_amdgcn_mfma_f32_16x16x32_bf16(a[1][kk], b, acc1, 0, 0, 0);
        }
        int colo = ct * 16 + lr;
#pragma unroll
        for (int r = 0; r < 4; ++r) {
            Y[(size_t)(row0 + kg * 4 + r) * 128 + colo] = f2bf(acc0[r]);
            Y[(size_t)(row0 + 16 + kg * 4 + r) * 128 + colo] = f2bf(acc1[r]);
        }
    }
}

// Fused double GEMM: Yu = X @ Wu, Yv = X @ Wv; X read once, both W in LDS.
__global__ __launch_bounds__(256) void k_gmm2(const ushort* __restrict__ Xb,
                                              const ushort* __restrict__ Wtu,
                                              const ushort* __restrict__ Wtv,
                                              ushort* __restrict__ Yu,
                                              ushort* __restrict__ Yv) {
    __shared__ ushort Ws[2][16384];
    int t = threadIdx.x;
    for (int i = t; i < 2048; i += 256) {
        int o = i * 16;
        int phys = o ^ (((o >> 8) & 7) << 4);
        *(uint4*)((char*)Ws[0] + phys) = *(const uint4*)((const char*)Wtu + o);
        *(uint4*)((char*)Ws[1] + phys) = *(const uint4*)((const char*)Wtv + o);
    }
    __syncthreads();
    int lane = t & 63;
    int kg = lane >> 4;
    int lr = lane & 15;
    int row0 = blockIdx.x * 128 + (t >> 6) * 32;
    short8v a[2][4];
#pragma unroll
    for (int s = 0; s < 2; ++s)
#pragma unroll
        for (int kk = 0; kk < 4; ++kk)
            a[s][kk] = *(const short8v*)((const char*)Xb +
                ((size_t)(row0 + s * 16 + lr) * 128 + kk * 32 + kg * 8) * 2);
#pragma unroll
    for (int ct = 0; ct < 8; ++ct) {
        int c = ct * 16 + lr;
        f32x4 au0 = {0.f, 0.f, 0.f, 0.f};
        f32x4 au1 = {0.f, 0.f, 0.f, 0.f};
        f32x4 av0 = {0.f, 0.f, 0.f, 0.f};
        f32x4 av1 = {0.f, 0.f, 0.f, 0.f};
#pragma unroll
        for (int kk = 0; kk < 4; ++kk) {
            int o = c * 256 + kk * 64 + kg * 16;
            int phys = o ^ ((c & 7) << 4);
            short8v bu = *(const short8v*)((const char*)Ws[0] + phys);
            short8v bv = *(const short8v*)((const char*)Ws[1] + phys);
            au0 = __builtin_amdgcn_mfma_f32_16x16x32_bf16(a[0][kk], bu, au0, 0, 0, 0);
            au1 = __builtin_amdgcn_mfma_f32_16x16x32_bf16(a[1][kk], bu, au1, 0, 0, 0);
            av0 = __builtin_amdgcn_mfma_f32_16x16x32_bf16(a[0][kk], bv, av0, 0, 0, 0);
            av1 = __builtin_amdgcn_mfma_f32_16x16x32_bf16(a[1][kk], bv, av1, 0, 0, 0);
        }
        int colo = ct * 16 + lr;
#pragma unroll
        for (int r = 0; r < 4; ++r) {
            Yu[(size_t)(row0 + kg * 4 + r) * 128 + colo] = f2bf(au0[r]);
            Yu[(size_t)(row0 + 16 + kg * 4 + r) * 128 + colo] = f2bf(au1[r]);
            Yv[(size_t)(row0 + kg * 4 + r) * 128 + colo] = f2bf(av0[r]);
            Yv[(size_t)(row0 + 16 + kg * 4 + r) * 128 + colo] = f2bf(av1[r]);
        }
    }
}

// Edge-parallel fused edge stage (R9 empirical optimum): 16-lane group per CSR
// entry, 4 entries/group, all 8 row-loads issued before compute.
#define EPB 64
__global__ __launch_bounds__(256) void k_edge(const int2* __restrict__ csr2,
                                              const ushort* __restrict__ u,
                                              const ushort* __restrict__ v,
                                              const float* __restrict__ bl1,
                                              const float* __restrict__ Wl2,
                                              const float* __restrict__ bl2,
                                              float* __restrict__ out) {
    int g = threadIdx.x >> 4;
    int l16 = threadIdx.x & 15;
    int base = blockIdx.x * EPB + g;

    float4 ba = *(const float4*)(bl1 + l16 * 8);
    float4 bb = *(const float4*)(bl1 + l16 * 8 + 4);
    float4 w0 = *(const float4*)(Wl2 + l16 * 16);
    float4 w1 = *(const float4*)(Wl2 + l16 * 16 + 4);
    float4 w2 = *(const float4*)(Wl2 + l16 * 16 + 8);
    float4 w3 = *(const float4*)(Wl2 + l16 * 16 + 12);
    float b20 = bl2[0], b21 = bl2[1];

    int2 e0 = csr2[base];
    int2 e1 = csr2[base + 16];
    int2 e2 = csr2[base + 32];
    int2 e3 = csr2[base + 48];
    uint4 uu0 = *(const uint4*)((const uint*)(u + (size_t)((uint)e0.x & 0xffffu) * H) + l16 * 4);
    uint4 vv0 = *(const uint4*)((const uint*)(v + (size_t)((uint)e0.x >> 16) * H) + l16 * 4);
    uint4 uu1 = *(const uint4*)((const uint*)(u + (size_t)((uint)e1.x & 0xffffu) * H) + l16 * 4);
    uint4 vv1 = *(const uint4*)((const uint*)(v + (size_t)((uint)e1.x >> 16) * H) + l16 * 4);
    uint4 uu2 = *(const uint4*)((const uint*)(u + (size_t)((uint)e2.x & 0xffffu) * H) + l16 * 4);
    uint4 vv2 = *(const uint4*)((const uint*)(v + (size_t)((uint)e2.x >> 16) * H) + l16 * 4);
    uint4 uu3 = *(const uint4*)((const uint*)(u + (size_t)((uint)e3.x & 0xffffu) * H) + l16 * 4);
    uint4 vv3 = *(const uint4*)((const uint*)(v + (size_t)((uint)e3.x >> 16) * H) + l16 * 4);

#pragma unroll
    for (int q = 0; q < 4; ++q) {
        uint4 uu = (q == 0) ? uu0 : (q == 1) ? uu1 : (q == 2) ? uu2 : uu3;
        uint4 vv = (q == 0) ? vv0 : (q == 1) ? vv1 : (q == 2) ? vv2 : vv3;
        int eid = (q == 0) ? e0.y : (q == 1) ? e1.y : (q == 2) ? e2.y : e3.y;
        float h0 = fmaxf(bflo(uu.x) + bflo(vv.x) + ba.x, 0.f);
        float h1 = fmaxf(bfhi(uu.x) + bfhi(vv.x) + ba.y, 0.f);
        float h2 = fmaxf(bflo(uu.y) + bflo(vv.y) + ba.z, 0.f);
        float h3 = fmaxf(bfhi(uu.y) + bfhi(vv.y) + ba.w, 0.f);
        float h4 = fmaxf(bflo(uu.z) + bflo(vv.z) + bb.x, 0.f);
        float h5 = fmaxf(bfhi(uu.z) + bfhi(vv.z) + bb.y, 0.f);
        float h6 = fmaxf(bflo(uu.w) + bflo(vv.w) + bb.z, 0.f);
        float h7 = fmaxf(bfhi(uu.w) + bfhi(vv.w) + bb.w, 0.f);
        float p0 = h0 * w0.x + h1 * w0.z + h2 * w1.x + h3 * w1.z
                 + h4 * w2.x + h5 * w2.z + h6 * w3.x + h7 * w3.z;
        float p1 = h0 * w0.y + h1 * w0.w + h2 * w1.y + h3 * w1.w
                 + h4 * w2.y + h5 * w2.w + h6 * w3.y + h7 * w3.w;
#pragma unroll
        for (int m = 1; m < 16; m <<= 1) {
            p0 += __shfl_xor(p0, m, 64);
            p1 += __shfl_xor(p1, m, 64);
        }
        if (l16 == 0) {
            float2 o;
            o.x = fmaxf(p0 + b20, 0.f);
            o.y = fmaxf(p1 + b21, 0.f);
            *(float2*)(out + (size_t)eid * 2) = o;
        }
    }
}

extern "C" void kernel_launch(void* const* d_in, const int* in_sizes, int n_in,
                              void* d_out, int out_size, void* d_ws, size_t ws_size,
                              hipStream_t stream) {
    const float* x   = (const float*)d_in[0];
    const float* W1  = (const float*)d_in[1];
    const float* b1  = (const float*)d_in[2];
    const float* W2  = (const float*)d_in[3];
    const float* b2  = (const float*)d_in[4];
    const float* Wl1 = (const float*)d_in[5];
    const float* bl1 = (const float*)d_in[6];
    const float* Wl2 = (const float*)d_in[7];
    const float* bl2 = (const float*)d_in[8];
    const int*   ei  = (const int*)d_in[9];
    const int* src = ei;
    const int* dst = ei + NE;
    float* out = (float*)d_out;

    char* ws = (char*)d_ws;
    size_t off = 0;
    auto alloc = [&](size_t bytes) -> void* {
        void* p = ws + off;
        off = (off + bytes + 255) & ~(size_t)255;
        return p;
    };
    float*  dinv     = (float*)alloc(NN * 4);
    int*    rowstart = (int*)alloc((NN + 1) * 4);
    int*    Bbase    = (int*)alloc((NB + 1) * 4);
    int*    Hg       = (int*)alloc((size_t)NBE * NB * 4);
    int*    Offb     = (int*)alloc((size_t)NBE * NB * 4);
    int2*   csr2     = (int2*)alloc((size_t)NE * 8);
    ushort* hbf      = (ushort*)alloc((size_t)NP * H * 2);   // h1 then h2
    ushort* pbf      = (ushort*)alloc((size_t)NP * H * 2);   // p1 then p2
    ushort* ubf      = (ushort*)alloc((size_t)NP * H * 2);
    ushort* vbf      = (ushort*)alloc((size_t)NP * H * 2);
    ushort* Wt2      = (ushort*)alloc(128 * 128 * 2);
    ushort* Wtu      = (ushort*)alloc(128 * 128 * 2);
    ushort* Wtv      = (ushort*)alloc(128 * 128 * 2);
    int2*   bin      = (int2*)ubf;  // alias; dead before k_gmm2 writes ubf

    k_hist<<<NBE, 512, 0, stream>>>(dst, Hg);
    k_scans<<<1, 512, 0, stream>>>(Hg, Bbase, Offb);
    k_scatter<<<NBE, 512, 0, stream>>>(src, dst, Offb, bin);
    k_binB<<<NB, 256, 0, stream>>>(Bbase, bin, csr2, rowstart, dinv);
    k_wcvt<<<192, 256, 0, stream>>>(W2, Wl1, Wt2, Wtu, Wtv);

    k_xw1<<<NN / 2, 256, 0, stream>>>(x, W1, hbf);                                // h1
    k_agg<<<NN / 4, 256, 0, stream>>>(hbf, dinv, rowstart, csr2, b1, (uint*)pbf); // p1
    k_gmm<<<NP / 128, 256, 0, stream>>>(pbf, Wt2, hbf);                           // h2
    k_agg<<<NN / 4, 256, 0, stream>>>(hbf, dinv, rowstart, csr2, b2, (uint*)pbf); // p2
    k_gmm2<<<NP / 128, 256, 0, stream>>>(pbf, Wtu, Wtv, ubf, vbf);                // u, v
    k_edge<<<NE / EPB, 256, 0, stream>>>(csr2, ubf, vbf, bl1, Wl2, bl2, out);
}

// Round 13
// 186.786 us; speedup vs baseline: 2.1674x; 1.0712x over previous
//
#include <hip/hip_runtime.h>

#define NN 50000
#define NE 800000
#define F_IN 8
#define H 128
#define BSH 7
#define NB ((NN + 127) >> BSH)         // 391 buckets, 128 dsts each
#define EBLK 4096
#define NBE ((NE + EBLK - 1) / EBLK)   // 196 edge blocks
#define NP 50048                       // padded rows; 50048 = 391*128 exactly

typedef unsigned int uint;
typedef unsigned short ushort;
typedef __attribute__((ext_vector_type(8))) short short8v;
typedef __attribute__((ext_vector_type(4))) float f32x4;

__device__ __forceinline__ ushort f2bf(float f) {
    uint u = __float_as_uint(f);
    uint r = (u + 0x7fffu + ((u >> 16) & 1u)) >> 16;
    return (ushort)r;
}
__device__ __forceinline__ float bflo(uint u) { return __uint_as_float(u << 16); }
__device__ __forceinline__ float bfhi(uint u) { return __uint_as_float(u & 0xffff0000u); }

// ---- fused: bucket histogram (blocks 0..NBE-1) ∥ weight transpose+cvt (blocks NBE..NBE+95) ----
__global__ __launch_bounds__(512) void k_hw(const int* __restrict__ dst,
                                            int* __restrict__ Hg,
                                            const float* __restrict__ W2,
                                            const float* __restrict__ Wl1,
                                            ushort* __restrict__ Wt2,
                                            ushort* __restrict__ Wtu,
                                            ushort* __restrict__ Wtv) {
    int t = threadIdx.x, blk = blockIdx.x;
    if (blk < NBE) {
        __shared__ int h[NB];
        for (int b = t; b < NB; b += 512) h[b] = 0;
        __syncthreads();
        int e0 = blk * EBLK;
        int e1 = e0 + EBLK; if (e1 > NE) e1 = NE;
        for (int i = e0 + t; i < e1; i += 512) atomicAdd(&h[dst[i] >> BSH], 1);
        __syncthreads();
        for (int b = t; b < NB; b += 512) Hg[blk * NB + b] = h[b];
    } else {
        int id = (blk - NBE) * 512 + t;    // 96*512 = 49152 = 3*16384
        int m = id >> 14;
        int r = id & 16383;
        int c = r >> 7, k = r & 127;
        float v;
        ushort* dstp;
        if (m == 0)      { v = W2[k * 128 + c];          dstp = Wt2; }
        else if (m == 1) { v = Wl1[k * 128 + c];         dstp = Wtu; }
        else             { v = Wl1[(128 + k) * 128 + c]; dstp = Wtv; }
        dstp[r] = f2bf(v);
    }
}

// ---- fused: scans (block 0) ∥ xw1 (blocks 1..12500) ----
// scans: bucket bases (col-sum+scan over Hg) AND per-(edge-block,bucket) offsets.
// xw1:   h[n][j] = sum_k x[n][k]*W1[k][j], bf16 out; 4 nodes per 512-thr block.
__global__ __launch_bounds__(512) void k_sx(const int* __restrict__ Hg,
                                            int* __restrict__ Bbase,
                                            int* __restrict__ Off,
                                            const float* __restrict__ x,
                                            const float* __restrict__ W1,
                                            ushort* __restrict__ h) {
    int t = threadIdx.x;
    if (blockIdx.x == 0) {
        __shared__ int s[512];
        int acc = 0;
        if (t < NB)
            for (int e = 0; e < NBE; ++e) acc += Hg[e * NB + t];
        s[t] = acc;
        __syncthreads();
        for (int off = 1; off < 512; off <<= 1) {
            int v = (t >= off) ? s[t - off] : 0;
            __syncthreads();
            s[t] += v;
            __syncthreads();
        }
        int base = (t == 0) ? 0 : s[t - 1];
        if (t <= NB) Bbase[t] = base;
        if (t < NB) {
            int run = base;
            for (int e = 0; e < NBE; ++e) {
                Off[e * NB + t] = run;
                run += Hg[e * NB + t];
            }
        }
    } else {
        int n = (blockIdx.x - 1) * 4 + (t >> 7);
        int j = t & 127;
        const float* xr = x + n * F_IN;
        float acc = 0.f;
#pragma unroll
        for (int k = 0; k < F_IN; ++k) acc += xr[k] * W1[k * H + j];
        h[n * H + j] = f2bf(acc);
    }
}

// ---- deterministic scatter into bucket-contiguous regions ----
__global__ __launch_bounds__(512) void k_scatter(const int* __restrict__ src,
                                                 const int* __restrict__ dst,
                                                 const int* __restrict__ Off,
                                                 int2* __restrict__ bin) {
    __shared__ int cur[NB];
    int t = threadIdx.x, blk = blockIdx.x;
    for (int b = t; b < NB; b += 512) cur[b] = Off[blk * NB + b];
    __syncthreads();
    int e0 = blk * EBLK;
    int e1 = e0 + EBLK; if (e1 > NE) e1 = NE;
    for (int i = e0 + t; i < e1; i += 512) {
        int d = dst[i];
        int b = d >> BSH;
        int pos = atomicAdd(&cur[b], 1);
        bin[pos] = make_int2((src[i] & 0xffff) | ((d & ((1 << BSH) - 1)) << 16), i);
    }
}

// ---- bucket -> per-dst CSR; derives rowstart + dinv ----
__global__ __launch_bounds__(256) void k_binB(const int* __restrict__ Bbase,
                                              const int2* __restrict__ bin,
                                              int2* __restrict__ csr2,
                                              int* __restrict__ rowstart,
                                              float* __restrict__ dinv) {
    int b = blockIdx.x, t = threadIdx.x;
    __shared__ int cnt[128];
    __shared__ int cur[128];
    int base = Bbase[b];
    int end = Bbase[b + 1];
    if (t < 128) cnt[t] = 0;
    __syncthreads();
    for (int idx = base + t; idx < end; idx += 256)
        atomicAdd(&cnt[(uint)bin[idx].x >> 16], 1);
    __syncthreads();
    int myc = (t < 128) ? cnt[t] : 0;
    for (int off = 1; off < 128; off <<= 1) {
        int v = (t >= off && t < 128) ? cnt[t - off] : 0;
        __syncthreads();
        if (t < 128) cnt[t] += v;
        __syncthreads();
    }
    if (t < 128) {
        int startpos = base + cnt[t] - myc;
        int n = (b << BSH) + t;
        if (n < NN) {
            rowstart[n] = startpos;
            dinv[n] = rsqrtf((float)(myc + 1));
        }
        if (b == NB - 1 && t == 127) rowstart[NN] = NE;
        cur[t] = startpos;
    }
    __syncthreads();
    for (int idx = base + t; idx < end; idx += 256) {
        int2 e = bin[idx];
        int ld = (int)((uint)e.x >> 16);
        uint d = (uint)((b << BSH) + ld);
        int pos = atomicAdd(&cur[ld], 1);
        csr2[pos] = make_int2((int)(((uint)e.x & 0xffffu) | (d << 16)), e.y);
    }
}

// p[n] = relu( h[n]*dinv[n]^2 + sum_s h[s]*dinv[s]*dinv[n] + bias ), bf16 out
__global__ __launch_bounds__(256) void k_agg(const ushort* __restrict__ h,
                                             const float* __restrict__ dinv,
                                             const int* __restrict__ rowstart,
                                             const int2* __restrict__ csr2,
                                             const float* __restrict__ bias,
                                             uint* __restrict__ p) {
    int n = blockIdx.x * 4 + (threadIdx.x >> 6);
    int t = threadIdx.x & 63;
    float dn = dinv[n];
    uint us = ((const uint*)(h + (size_t)n * H))[t];
    float w0 = dn * dn;
    float ax = bflo(us) * w0;
    float ay = bfhi(us) * w0;
    int lo = rowstart[n], hi = rowstart[n + 1];
    int i = lo;
    for (; i + 7 < hi; i += 8) {
        int s0 = csr2[i + 0].x & 0xffff;
        int s1 = csr2[i + 1].x & 0xffff;
        int s2 = csr2[i + 2].x & 0xffff;
        int s3 = csr2[i + 3].x & 0xffff;
        int s4 = csr2[i + 4].x & 0xffff;
        int s5 = csr2[i + 5].x & 0xffff;
        int s6 = csr2[i + 6].x & 0xffff;
        int s7 = csr2[i + 7].x & 0xffff;
        uint u0 = ((const uint*)(h + (size_t)s0 * H))[t];
        uint u1 = ((const uint*)(h + (size_t)s1 * H))[t];
        uint u2 = ((const uint*)(h + (size_t)s2 * H))[t];
        uint u3 = ((const uint*)(h + (size_t)s3 * H))[t];
        uint u4 = ((const uint*)(h + (size_t)s4 * H))[t];
        uint u5 = ((const uint*)(h + (size_t)s5 * H))[t];
        uint u6 = ((const uint*)(h + (size_t)s6 * H))[t];
        uint u7 = ((const uint*)(h + (size_t)s7 * H))[t];
        float wa = dinv[s0] * dn, wb = dinv[s1] * dn, wc = dinv[s2] * dn, wd = dinv[s3] * dn;
        float we = dinv[s4] * dn, wf = dinv[s5] * dn, wg = dinv[s6] * dn, wh = dinv[s7] * dn;
        ax += bflo(u0) * wa + bflo(u1) * wb + bflo(u2) * wc + bflo(u3) * wd
            + bflo(u4) * we + bflo(u5) * wf + bflo(u6) * wg + bflo(u7) * wh;
        ay += bfhi(u0) * wa + bfhi(u1) * wb + bfhi(u2) * wc + bfhi(u3) * wd
            + bfhi(u4) * we + bfhi(u5) * wf + bfhi(u6) * wg + bfhi(u7) * wh;
    }
    for (; i < hi; ++i) {
        int s0 = csr2[i].x & 0xffff;
        uint u0 = ((const uint*)(h + (size_t)s0 * H))[t];
        float wa = dinv[s0] * dn;
        ax += bflo(u0) * wa;
        ay += bfhi(u0) * wa;
    }
    float2 bb = ((const float2*)bias)[t];
    ushort rx = f2bf(fmaxf(ax + bb.x, 0.f));
    ushort ry = f2bf(fmaxf(ay + bb.y, 0.f));
    p[(size_t)n * 64 + t] = (uint)rx | ((uint)ry << 16);
}

// MFMA bf16 GEMM: Y = X @ W (Wt[c][k] transposed input)
__global__ __launch_bounds__(256) void k_gmm(const ushort* __restrict__ Xb,
                                             const ushort* __restrict__ Wt,
                                             ushort* __restrict__ Y) {
    __shared__ ushort Ws[16384];
    int t = threadIdx.x;
    for (int i = t; i < 2048; i += 256) {
        int o = i * 16;
        int phys = o ^ (((o >> 8) & 7) << 4);
        *(uint4*)((char*)Ws + phys) = *(const uint4*)((const char*)Wt + o);
    }
    __syncthreads();
    int lane = t & 63;
    int kg = lane >> 4;
    int lr = lane & 15;
    int row0 = blockIdx.x * 128 + (t >> 6) * 32;
    short8v a[2][4];
#pragma unroll
    for (int s = 0; s < 2; ++s)
#pragma unroll
        for (int kk = 0; kk < 4; ++kk)
            a[s][kk] = *(const short8v*)((const char*)Xb +
                ((size_t)(row0 + s * 16 + lr) * 128 + kk * 32 + kg * 8) * 2);
#pragma unroll
    for (int ct = 0; ct < 8; ++ct) {
        int c = ct * 16 + lr;
        f32x4 acc0 = {0.f, 0.f, 0.f, 0.f};
        f32x4 acc1 = {0.f, 0.f, 0.f, 0.f};
#pragma unroll
        for (int kk = 0; kk < 4; ++kk) {
            int o = c * 256 + kk * 64 + kg * 16;
            int phys = o ^ ((c & 7) << 4);
            short8v b = *(const short8v*)((const char*)Ws + phys);
            acc0 = __builtin_amdgcn_mfma_f32_16x16x32_bf16(a[0][kk], b, acc0, 0, 0, 0);
            acc1 = __builtin_amdgcn_mfma_f32_16x16x32_bf16(a[1][kk], b, acc1, 0, 0, 0);
        }
        int colo = ct * 16 + lr;
#pragma unroll
        for (int r = 0; r < 4; ++r) {
            Y[(size_t)(row0 + kg * 4 + r) * 128 + colo] = f2bf(acc0[r]);
            Y[(size_t)(row0 + 16 + kg * 4 + r) * 128 + colo] = f2bf(acc1[r]);
        }
    }
}

// Fused double GEMM: Yu = X @ Wu, Yv = X @ Wv; X read once, both W in LDS.
__global__ __launch_bounds__(256) void k_gmm2(const ushort* __restrict__ Xb,
                                              const ushort* __restrict__ Wtu,
                                              const ushort* __restrict__ Wtv,
                                              ushort* __restrict__ Yu,
                                              ushort* __restrict__ Yv) {
    __shared__ ushort Ws[2][16384];
    int t = threadIdx.x;
    for (int i = t; i < 2048; i += 256) {
        int o = i * 16;
        int phys = o ^ (((o >> 8) & 7) << 4);
        *(uint4*)((char*)Ws[0] + phys) = *(const uint4*)((const char*)Wtu + o);
        *(uint4*)((char*)Ws[1] + phys) = *(const uint4*)((const char*)Wtv + o);
    }
    __syncthreads();
    int lane = t & 63;
    int kg = lane >> 4;
    int lr = lane & 15;
    int row0 = blockIdx.x * 128 + (t >> 6) * 32;
    short8v a[2][4];
#pragma unroll
    for (int s = 0; s < 2; ++s)
#pragma unroll
        for (int kk = 0; kk < 4; ++kk)
            a[s][kk] = *(const short8v*)((const char*)Xb +
                ((size_t)(row0 + s * 16 + lr) * 128 + kk * 32 + kg * 8) * 2);
#pragma unroll
    for (int ct = 0; ct < 8; ++ct) {
        int c = ct * 16 + lr;
        f32x4 au0 = {0.f, 0.f, 0.f, 0.f};
        f32x4 au1 = {0.f, 0.f, 0.f, 0.f};
        f32x4 av0 = {0.f, 0.f, 0.f, 0.f};
        f32x4 av1 = {0.f, 0.f, 0.f, 0.f};
#pragma unroll
        for (int kk = 0; kk < 4; ++kk) {
            int o = c * 256 + kk * 64 + kg * 16;
            int phys = o ^ ((c & 7) << 4);
            short8v bu = *(const short8v*)((const char*)Ws[0] + phys);
            short8v bv = *(const short8v*)((const char*)Ws[1] + phys);
            au0 = __builtin_amdgcn_mfma_f32_16x16x32_bf16(a[0][kk], bu, au0, 0, 0, 0);
            au1 = __builtin_amdgcn_mfma_f32_16x16x32_bf16(a[1][kk], bu, au1, 0, 0, 0);
            av0 = __builtin_amdgcn_mfma_f32_16x16x32_bf16(a[0][kk], bv, av0, 0, 0, 0);
            av1 = __builtin_amdgcn_mfma_f32_16x16x32_bf16(a[1][kk], bv, av1, 0, 0, 0);
        }
        int colo = ct * 16 + lr;
#pragma unroll
        for (int r = 0; r < 4; ++r) {
            Yu[(size_t)(row0 + kg * 4 + r) * 128 + colo] = f2bf(au0[r]);
            Yu[(size_t)(row0 + 16 + kg * 4 + r) * 128 + colo] = f2bf(au1[r]);
            Yv[(size_t)(row0 + kg * 4 + r) * 128 + colo] = f2bf(av0[r]);
            Yv[(size_t)(row0 + 16 + kg * 4 + r) * 128 + colo] = f2bf(av1[r]);
        }
    }
}

// Edge-parallel fused edge stage (R9 empirical optimum): 16-lane group per CSR
// entry, 4 entries/group, all 8 row-loads issued before compute.
#define EPB 64
__global__ __launch_bounds__(256) void k_edge(const int2* __restrict__ csr2,
                                              const ushort* __restrict__ u,
                                              const ushort* __restrict__ v,
                                              const float* __restrict__ bl1,
                                              const float* __restrict__ Wl2,
                                              const float* __restrict__ bl2,
                                              float* __restrict__ out) {
    int g = threadIdx.x >> 4;
    int l16 = threadIdx.x & 15;
    int base = blockIdx.x * EPB + g;

    float4 ba = *(const float4*)(bl1 + l16 * 8);
    float4 bb = *(const float4*)(bl1 + l16 * 8 + 4);
    float4 w0 = *(const float4*)(Wl2 + l16 * 16);
    float4 w1 = *(const float4*)(Wl2 + l16 * 16 + 4);
    float4 w2 = *(const float4*)(Wl2 + l16 * 16 + 8);
    float4 w3 = *(const float4*)(Wl2 + l16 * 16 + 12);
    float b20 = bl2[0], b21 = bl2[1];

    int2 e0 = csr2[base];
    int2 e1 = csr2[base + 16];
    int2 e2 = csr2[base + 32];
    int2 e3 = csr2[base + 48];
    uint4 uu0 = *(const uint4*)((const uint*)(u + (size_t)((uint)e0.x & 0xffffu) * H) + l16 * 4);
    uint4 vv0 = *(const uint4*)((const uint*)(v + (size_t)((uint)e0.x >> 16) * H) + l16 * 4);
    uint4 uu1 = *(const uint4*)((const uint*)(u + (size_t)((uint)e1.x & 0xffffu) * H) + l16 * 4);
    uint4 vv1 = *(const uint4*)((const uint*)(v + (size_t)((uint)e1.x >> 16) * H) + l16 * 4);
    uint4 uu2 = *(const uint4*)((const uint*)(u + (size_t)((uint)e2.x & 0xffffu) * H) + l16 * 4);
    uint4 vv2 = *(const uint4*)((const uint*)(v + (size_t)((uint)e2.x >> 16) * H) + l16 * 4);
    uint4 uu3 = *(const uint4*)((const uint*)(u + (size_t)((uint)e3.x & 0xffffu) * H) + l16 * 4);
    uint4 vv3 = *(const uint4*)((const uint*)(v + (size_t)((uint)e3.x >> 16) * H) + l16 * 4);

#pragma unroll
    for (int q = 0; q < 4; ++q) {
        uint4 uu = (q == 0) ? uu0 : (q == 1) ? uu1 : (q == 2) ? uu2 : uu3;
        uint4 vv = (q == 0) ? vv0 : (q == 1) ? vv1 : (q == 2) ? vv2 : vv3;
        int eid = (q == 0) ? e0.y : (q == 1) ? e1.y : (q == 2) ? e2.y : e3.y;
        float h0 = fmaxf(bflo(uu.x) + bflo(vv.x) + ba.x, 0.f);
        float h1 = fmaxf(bfhi(uu.x) + bfhi(vv.x) + ba.y, 0.f);
        float h2 = fmaxf(bflo(uu.y) + bflo(vv.y) + ba.z, 0.f);
        float h3 = fmaxf(bfhi(uu.y) + bfhi(vv.y) + ba.w, 0.f);
        float h4 = fmaxf(bflo(uu.z) + bflo(vv.z) + bb.x, 0.f);
        float h5 = fmaxf(bfhi(uu.z) + bfhi(vv.z) + bb.y, 0.f);
        float h6 = fmaxf(bflo(uu.w) + bflo(vv.w) + bb.z, 0.f);
        float h7 = fmaxf(bfhi(uu.w) + bfhi(vv.w) + bb.w, 0.f);
        float p0 = h0 * w0.x + h1 * w0.z + h2 * w1.x + h3 * w1.z
                 + h4 * w2.x + h5 * w2.z + h6 * w3.x + h7 * w3.z;
        float p1 = h0 * w0.y + h1 * w0.w + h2 * w1.y + h3 * w1.w
                 + h4 * w2.y + h5 * w2.w + h6 * w3.y + h7 * w3.w;
#pragma unroll
        for (int m = 1; m < 16; m <<= 1) {
            p0 += __shfl_xor(p0, m, 64);
            p1 += __shfl_xor(p1, m, 64);
        }
        if (l16 == 0) {
            float2 o;
            o.x = fmaxf(p0 + b20, 0.f);
            o.y = fmaxf(p1 + b21, 0.f);
            *(float2*)(out + (size_t)eid * 2) = o;
        }
    }
}

extern "C" void kernel_launch(void* const* d_in, const int* in_sizes, int n_in,
                              void* d_out, int out_size, void* d_ws, size_t ws_size,
                              hipStream_t stream) {
    const float* x   = (const float*)d_in[0];
    const float* W1  = (const float*)d_in[1];
    const float* b1  = (const float*)d_in[2];
    const float* W2  = (const float*)d_in[3];
    const float* b2  = (const float*)d_in[4];
    const float* Wl1 = (const float*)d_in[5];
    const float* bl1 = (const float*)d_in[6];
    const float* Wl2 = (const float*)d_in[7];
    const float* bl2 = (const float*)d_in[8];
    const int*   ei  = (const int*)d_in[9];
    const int* src = ei;
    const int* dst = ei + NE;
    float* out = (float*)d_out;

    char* ws = (char*)d_ws;
    size_t off = 0;
    auto alloc = [&](size_t bytes) -> void* {
        void* p = ws + off;
        off = (off + bytes + 255) & ~(size_t)255;
        return p;
    };
    float*  dinv     = (float*)alloc(NN * 4);
    int*    rowstart = (int*)alloc((NN + 1) * 4);
    int*    Bbase    = (int*)alloc((NB + 1) * 4);
    int*    Hg       = (int*)alloc((size_t)NBE * NB * 4);
    int*    Offb     = (int*)alloc((size_t)NBE * NB * 4);
    int2*   csr2     = (int2*)alloc((size_t)NE * 8);
    ushort* hbf      = (ushort*)alloc((size_t)NP * H * 2);   // h1 then h2
    ushort* pbf      = (ushort*)alloc((size_t)NP * H * 2);   // p1 then p2
    ushort* ubf      = (ushort*)alloc((size_t)NP * H * 2);
    ushort* vbf      = (ushort*)alloc((size_t)NP * H * 2);
    ushort* Wt2      = (ushort*)alloc(128 * 128 * 2);
    ushort* Wtu      = (ushort*)alloc(128 * 128 * 2);
    ushort* Wtv      = (ushort*)alloc(128 * 128 * 2);
    int2*   bin      = (int2*)ubf;  // alias; dead before k_gmm2 writes ubf

    k_hw<<<NBE + 96, 512, 0, stream>>>(dst, Hg, W2, Wl1, Wt2, Wtu, Wtv);
    k_sx<<<1 + NN / 4, 512, 0, stream>>>(Hg, Bbase, Offb, x, W1, hbf);
    k_scatter<<<NBE, 512, 0, stream>>>(src, dst, Offb, bin);
    k_binB<<<NB, 256, 0, stream>>>(Bbase, bin, csr2, rowstart, dinv);

    k_agg<<<NN / 4, 256, 0, stream>>>(hbf, dinv, rowstart, csr2, b1, (uint*)pbf); // p1
    k_gmm<<<NP / 128, 256, 0, stream>>>(pbf, Wt2, hbf);                           // h2
    k_agg<<<NN / 4, 256, 0, stream>>>(hbf, dinv, rowstart, csr2, b2, (uint*)pbf); // p2
    k_gmm2<<<NP / 128, 256, 0, stream>>>(pbf, Wtu, Wtv, ubf, vbf);                // u, v
    k_edge<<<NE / EPB, 256, 0, stream>>>(csr2, ubf, vbf, bl1, Wl2, bl2, out);
}